// Round 23
// baseline (193.001 us; speedup 1.0000x reference)
//
#include <hip/hip_runtime.h>
#include <hip/hip_bf16.h>

#define B_    16
#define L_    1024
#define DM    384
#define DIP   1676
#define NIP   1664
#define DI    768
#define CONVD 896
#define NH    12
#define HD    64
#define DS    64
#define NCH   4
#define CH    256
#define EPS_  1e-5f

typedef unsigned short u16;
typedef unsigned int   u32;
typedef __attribute__((ext_vector_type(8))) _Float16 f16x8;
typedef __attribute__((ext_vector_type(4))) float f32x4;

union U4 { uint4 v; u16 s[8]; };

#define SWZ(row, slot) (((row) << 7) + ((((slot) ^ ((row) & 7)) & 7) << 4))

__device__ __forceinline__ u16 f2h(float v) { return __builtin_bit_cast(u16, (_Float16)v); }
__device__ __forceinline__ float h2f(u16 h) { return (float)__builtin_bit_cast(_Float16, h); }

// ---------------- K_prep: fused cvtA + cvtWh(ipw) + cvtWh(opw) + dtp ----------------
__global__ __launch_bounds__(256) void k_prep(
    const float* __restrict__ u, const float* __restrict__ ipw,
    const float* __restrict__ opw,
    const float* __restrict__ dtb, const float* __restrict__ A_log,
    u16* __restrict__ Ah, u16* __restrict__ Whip, u16* __restrict__ Woh,
    float* __restrict__ dt, float* __restrict__ dAcs, float* __restrict__ cdecay)
{
  __shared__ float smem[32 * 129 + 8];
  const int bid = blockIdx.x;
  const int t = threadIdx.x;
  if (bid < 1536) {
    float (*Ls)[129] = (float(*)[129])smem;
    const int l0 = (bid & 7) * 128;
    const int k0 = ((bid >> 3) % 12) * 32;
    const int b  = bid / 96;
#pragma unroll
    for (int r = 0; r < 4; ++r) {
      int idx = r * 256 + t;
      int kk = idx >> 5, q = idx & 31;
      float4 v = *(const float4*)&u[((size_t)(b * DM + k0 + kk)) * L_ + l0 + q * 4];
      Ls[kk][q * 4 + 0] = v.x; Ls[kk][q * 4 + 1] = v.y;
      Ls[kk][q * 4 + 2] = v.z; Ls[kk][q * 4 + 3] = v.w;
    }
    __syncthreads();
#pragma unroll
    for (int it = 0; it < 2; ++it) {
      int task = it * 256 + t;
      int l = task >> 2, kq = (task & 3) * 8;
      u32 hw[4];
#pragma unroll
      for (int j = 0; j < 4; ++j) {
        u16 h0 = f2h(Ls[kq + 2 * j + 0][l]);
        u16 h1 = f2h(Ls[kq + 2 * j + 1][l]);
        hw[j] = (u32)h0 | ((u32)h1 << 16);
      }
      size_t off = ((size_t)(b * L_ + l0 + l)) * DM + k0 + kq;
      *(uint4*)&Ah[off] = make_uint4(hw[0], hw[1], hw[2], hw[3]);
    }
  } else if (bid < 2160) {
    int i = (bid - 1536) * 256 + t;
    if (i < NIP * DM / 4) {
      int e = i * 4;
      float4 v = *(const float4*)&ipw[e];
      u16 h[4] = {f2h(v.x), f2h(v.y), f2h(v.z), f2h(v.w)};
      *(uint2*)&Whip[e] = make_uint2((u32)h[0] | ((u32)h[1] << 16), (u32)h[2] | ((u32)h[3] << 16));
    }
  } else if (bid < 2448) {
    int i = (bid - 2160) * 256 + t;
    if (i < DM * DI / 4) {
      int e = i * 4;
      float4 v = *(const float4*)&opw[e];
      u16 h[4] = {f2h(v.x), f2h(v.y), f2h(v.z), f2h(v.w)};
      *(uint2*)&Woh[e] = make_uint2((u32)h[0] | ((u32)h[1] << 16), (u32)h[2] | ((u32)h[3] << 16));
    }
  } else {
    float* wdt = smem;
    float* ws4 = smem + DM;
    const int bb = bid - 2448;
    const int bc = bb & 63;
    const int h  = bb >> 6;
    const int b  = bc >> 2, l0 = (bc & 3) * 256;
    const int lane = t & 63, w = t >> 6;
    for (int i = t; i < DM; i += 256) wdt[i] = ipw[(size_t)(NIP + h) * DM + i];
    __syncthreads();
    const float* ub = u + (size_t)b * DM * L_ + l0 + t;
    float acc = 0.f;
#pragma unroll 8
    for (int k = 0; k < DM; ++k)
      acc = fmaf(ub[(size_t)k * L_], wdt[k], acc);
    const size_t row = (size_t)bc * 256 + t;
    float logit = acc + dtb[h];
    float dtv = (logit > 20.f) ? logit : log1pf(expf(logit));
    dt[row * NH + h] = dtv;
    float xv = dtv * (-expf(A_log[h]));
#pragma unroll
    for (int off = 1; off < 64; off <<= 1) {
      float y = __shfl_up(xv, off, 64);
      if (lane >= off) xv += y;
    }
    if (lane == 63) ws4[w] = xv;
    __syncthreads();
    float add = 0.f;
#pragma unroll
    for (int i = 0; i < 4; ++i) if (i < w) add += ws4[i];
    xv += add;
    dAcs[row * NH + h] = xv;
    if (t == 255) cdecay[bc * NH + h] = expf(xv);
  }
}

// 2-stream staging of one 128x32 u16 K-tile set (stride KS) into buffer `bufbase`
#define STAGE2S(bufbase, k0, KS) do {                                                           \
  _Pragma("unroll")                                                                             \
  for (int i_ = 0; i_ < 2; ++i_) {                                                              \
    int S_ = i_ * 256 + t;                                                                      \
    int m_ = S_ >> 2;                                                                           \
    int g_ = (S_ ^ (m_ >> 1)) & 3;                                                              \
    size_t goff_ = (size_t)m_ * (KS) + (k0) + g_ * 8;                                           \
    __builtin_amdgcn_global_load_lds((const __attribute__((address_space(1))) u32*)(g0 + goff_),\
        (__attribute__((address_space(3))) u32*)(lds + (bufbase) + S_ * 8), 16, 0, 0);          \
    __builtin_amdgcn_global_load_lds((const __attribute__((address_space(1))) u32*)(g2 + goff_),\
        (__attribute__((address_space(3))) u32*)(lds + (bufbase) + 4096 + S_ * 8), 16, 0, 0);   \
  }                                                                                             \
} while (0)

// ---------------- fp16 MFMA GEMM: in_proj — 128x128, 2-buffer counted-vmcnt + XCD swizzle ----------------
__global__ __launch_bounds__(256) void k_gemm1(
    const u16* __restrict__ Ah,
    const u16* __restrict__ Wh,
    u16* __restrict__ z, u16* __restrict__ xBC)
{
  __shared__ u16 lds[16384];
  const int t = threadIdx.x;
  const int lane = t & 63, wid = t >> 6;
  const int wr = wid >> 1, wc = wid & 1;
  const int gg = lane >> 4, mlo = lane & 15;
  const int xs = (blockIdx.x & 7) * 16 + (blockIdx.x >> 3);
  const int m0 = xs * 128, n0 = blockIdx.y * 128;
  f32x4 acc[4][4];
#pragma unroll
  for (int i = 0; i < 4; ++i)
#pragma unroll
    for (int j = 0; j < 4; ++j) acc[i][j] = (f32x4){0.f, 0.f, 0.f, 0.f};
  const u16* g0 = Ah + (size_t)m0 * DM;
  const u16* g2 = Wh + (size_t)n0 * DM;
  const int NT = DM / 32;
  STAGE2S(0, 0, DM);
  int cur = 0;
  for (int kt = 0; kt < NT; ++kt) {
    int ks = kt + 1; if (ks > NT - 1) ks = NT - 1;
    STAGE2S((cur ^ 1) * 8192, ks * 32, DM);
    asm volatile("s_waitcnt vmcnt(4)" ::: "memory");
    __builtin_amdgcn_s_barrier();
    const char* ldsb = (const char*)lds + cur * 16384;
    f16x8 fa[4], fb[4];
#pragma unroll
    for (int mf = 0; mf < 4; ++mf) {
      int m = wr * 64 + mf * 16 + mlo;
      int off = m * 64 + (((gg ^ (m >> 1)) & 3) << 4);
      fa[mf]  = *(const f16x8*)(ldsb + off);
    }
#pragma unroll
    for (int nf = 0; nf < 4; ++nf) {
      int n = wc * 64 + nf * 16 + mlo;
      int off = n * 64 + (((gg ^ (n >> 1)) & 3) << 4);
      fb[nf]  = *(const f16x8*)(ldsb + 8192 + off);
    }
#pragma unroll
    for (int mf = 0; mf < 4; ++mf)
#pragma unroll
      for (int nf = 0; nf < 4; ++nf)
        acc[mf][nf] = __builtin_amdgcn_mfma_f32_16x16x32_f16(fa[mf], fb[nf], acc[mf][nf], 0, 0, 0);
    __builtin_amdgcn_s_barrier();
    cur ^= 1;
  }
  const int rb = m0 + wr * 64 + (lane >> 4) * 4;
  const int cb = n0 + wc * 64 + mlo;
#pragma unroll
  for (int mf = 0; mf < 4; ++mf)
#pragma unroll
    for (int nf = 0; nf < 4; ++nf) {
      int col = cb + nf * 16;
#pragma unroll
      for (int r = 0; r < 4; ++r) {
        int row = rb + mf * 16 + r;
        float v = acc[mf][nf][r];
        if (col < DI) z[(size_t)row * DI + col] = f2h(v);
        else xBC[(size_t)row * CONVD + (col - DI)] = f2h(v);
      }
    }
}

// ---------------- k_gemm2n: fused LayerNorm*z + out_proj GEMM ----------------
// A = normed(y)*z computed on the fly (reg-stage + transform + ds_write); W via DMA depth-1.
__global__ __launch_bounds__(256) void k_gemm2n(
    const u16* __restrict__ y16, const u16* __restrict__ z16,
    const float* __restrict__ nw, const float* __restrict__ nb,
    const u16* __restrict__ Woh,
    float* __restrict__ out)
{
  __shared__ u16 Ab[4096];            // 8KB A tile (single buffer)
  __shared__ u16 Wb[8192];            // 2 x 8KB W tiles
  __shared__ float wln[DI], bln[DI];
  __shared__ float muL[128], rsL[128];
  const int t = threadIdx.x;
  const int lane = t & 63, wid = t >> 6;
  const int wr = wid >> 1, wc = wid & 1;
  const int gg = lane >> 4, mlo = lane & 15;
  const int xs = (blockIdx.x & 7) * 16 + (blockIdx.x >> 3);
  const int m0 = xs * 128, n0 = blockIdx.y * 128;
  for (int i = t; i < DI; i += 256) { wln[i] = nw[i]; bln[i] = nb[i]; }
  // row stats: 2 threads per row of the 128-row m-tile
  {
    const int row = t >> 1, half = t & 1;
    const u16* yp = y16 + (size_t)(m0 + row) * DI + half * 384;
    float s = 0.f, sq = 0.f;
    for (int i = 0; i < 48; ++i) {
      U4 v; v.v = *(const uint4*)(yp + i * 8);
#pragma unroll
      for (int k = 0; k < 8; ++k) { float f = h2f(v.s[k]); s += f; sq = fmaf(f, f, sq); }
    }
    s  += __shfl_xor(s, 1, 64);
    sq += __shfl_xor(sq, 1, 64);
    if (half == 0) {
      float mu = s * (1.f / DI);
      float var = sq * (1.f / DI) - mu * mu;
      muL[row] = mu;
      rsL[row] = 1.f / sqrtf(var + EPS_);
    }
  }
  f32x4 acc[4][4];
#pragma unroll
  for (int i = 0; i < 4; ++i)
#pragma unroll
    for (int j = 0; j < 4; ++j) acc[i][j] = (f32x4){0.f, 0.f, 0.f, 0.f};
  const u16* g2 = Woh + (size_t)n0 * DI;
  const int NT = DI / 32;
  __syncthreads();                     // wln/bln, muL/rsL ready
  // prologue: DMA W(0) -> Wb buf0
#pragma unroll
  for (int i_ = 0; i_ < 2; ++i_) {
    int S_ = i_ * 256 + t;
    int n_ = S_ >> 2;
    int g_ = (S_ ^ (n_ >> 1)) & 3;
    size_t goff_ = (size_t)n_ * DI + g_ * 8;
    __builtin_amdgcn_global_load_lds((const __attribute__((address_space(1))) u32*)(g2 + goff_),
        (__attribute__((address_space(3))) u32*)(Wb + S_ * 8), 16, 0, 0);
  }
  int cur = 0;
  for (int kt = 0; kt < NT; ++kt) {
    __builtin_amdgcn_s_barrier();      // prior compute's A/W reads done
    const int k0 = kt * 32;
    // reg-load y,z tiles for this K-step (issued before W DMA)
    U4 yv[2], zv[2];
#pragma unroll
    for (int i_ = 0; i_ < 2; ++i_) {
      int S_ = i_ * 256 + t;
      int m_ = S_ >> 2;
      int g_ = (S_ ^ (m_ >> 1)) & 3;
      size_t go = (size_t)(m0 + m_) * DI + k0 + g_ * 8;
      yv[i_].v = *(const uint4*)(y16 + go);
      zv[i_].v = *(const uint4*)(z16 + go);
    }
    // DMA W(kt+1) into other buffer
    if (kt + 1 < NT) {
#pragma unroll
      for (int i_ = 0; i_ < 2; ++i_) {
        int S_ = i_ * 256 + t;
        int n_ = S_ >> 2;
        int g_ = (S_ ^ (n_ >> 1)) & 3;
        size_t goff_ = (size_t)n_ * DI + (kt + 1) * 32 + g_ * 8;
        __builtin_amdgcn_global_load_lds((const __attribute__((address_space(1))) u32*)(g2 + goff_),
            (__attribute__((address_space(3))) u32*)(Wb + (cur ^ 1) * 4096 + S_ * 8), 16, 0, 0);
      }
    }
    // transform + ds_write A (compiler inserts waits for yv/zv)
#pragma unroll
    for (int i_ = 0; i_ < 2; ++i_) {
      int S_ = i_ * 256 + t;
      int m_ = S_ >> 2;
      int g_ = (S_ ^ (m_ >> 1)) & 3;
      float mu = muL[m_], a = rsL[m_];
      float nma = mu * a;
      U4 o;
#pragma unroll
      for (int j = 0; j < 8; ++j) {
        int d = k0 + g_ * 8 + j;
        float v = h2f(yv[i_].s[j]);
        float on = fmaf(fmaf(v, a, -nma), wln[d], bln[d]);
        o.s[j] = f2h(on * h2f(zv[i_].s[j]));
      }
      *(uint4*)((char*)Ab + S_ * 16) = o.v;
    }
    asm volatile("s_waitcnt lgkmcnt(0)" ::: "memory");   // A ds_writes done (this wave)
    asm volatile("s_waitcnt vmcnt(2)" ::: "memory");     // W(kt) drained (older than yz+W(kt+1))
    __builtin_amdgcn_s_barrier();
    const char* ldA = (const char*)Ab;
    const char* ldW = (const char*)Wb + cur * 8192;
    f16x8 fa[4], fb[4];
#pragma unroll
    for (int mf = 0; mf < 4; ++mf) {
      int m = wr * 64 + mf * 16 + mlo;
      int off = m * 64 + (((gg ^ (m >> 1)) & 3) << 4);
      fa[mf] = *(const f16x8*)(ldA + off);
    }
#pragma unroll
    for (int nf = 0; nf < 4; ++nf) {
      int n = wc * 64 + nf * 16 + mlo;
      int off = n * 64 + (((gg ^ (n >> 1)) & 3) << 4);
      fb[nf] = *(const f16x8*)(ldW + off);
    }
#pragma unroll
    for (int mf = 0; mf < 4; ++mf)
#pragma unroll
      for (int nf = 0; nf < 4; ++nf)
        acc[mf][nf] = __builtin_amdgcn_mfma_f32_16x16x32_f16(fa[mf], fb[nf], acc[mf][nf], 0, 0, 0);
    cur ^= 1;
  }
  const int rb = m0 + wr * 64 + (lane >> 4) * 4;
  const int cb = n0 + wc * 64 + mlo;
#pragma unroll
  for (int mf = 0; mf < 4; ++mf)
#pragma unroll
    for (int nf = 0; nf < 4; ++nf) {
      int col = cb + nf * 16;
#pragma unroll
      for (int r = 0; r < 4; ++r) {
        int row = rb + mf * 16 + r;
        int b = row >> 10, l = row & 1023;
        out[((size_t)(b * DM + col)) * L_ + l] = acc[mf][nf][r];
      }
    }
}

// ---------------- K2: depthwise conv; x-channels -> pre-swizzled XT fp16 tiles; B/C fp16 ----------------
#define CC 16
__global__ __launch_bounds__(256) void k_conv(
    const u16* __restrict__ xBC, const float* __restrict__ cw,
    const float* __restrict__ cb,
    u16* __restrict__ XTh,
    u16* __restrict__ Bh,
    u16* __restrict__ Chh)
{
  __shared__ float Ls[18][32][CC];
  const int t  = threadIdx.x;
  const int c0 = blockIdx.x * CC;
  const int h0 = blockIdx.y * 16;
  const int b  = blockIdx.z;
#pragma unroll
  for (int k = 0; k < 9; ++k) {
    int f = k * 256 + t;
    int fc4 = f & 3, fw = (f >> 2) & 31, fr = f >> 7;
    int h = h0 + fr - 1;
    U4 v; v.v = make_uint4(0, 0, 0, 0);
    if (h >= 0 && h < 32) {
      uint2 p = *(const uint2*)&xBC[((size_t)(b * 1024 + h * 32 + fw)) * CONVD + c0 + fc4 * 4];
      v.v.x = p.x; v.v.y = p.y;
    }
    Ls[fr][fw][fc4 * 4 + 0] = h2f(v.s[0]);
    Ls[fr][fw][fc4 * 4 + 1] = h2f(v.s[1]);
    Ls[fr][fw][fc4 * 4 + 2] = h2f(v.s[2]);
    Ls[fr][fw][fc4 * 4 + 3] = h2f(v.s[3]);
  }
  const int c4 = t & 3;
  const int w  = (t >> 2) & 31;
  const int hb = t >> 7;
  float wt[4][9];
  float bias[4];
#pragma unroll
  for (int j = 0; j < 4; ++j) {
    int c = c0 + c4 * 4 + j;
    bias[j] = cb[c];
#pragma unroll
    for (int kb = 0; kb < 9; ++kb) wt[j][kb] = cw[c * 9 + kb];
  }
  __syncthreads();
  const bool isx = (c0 < DI);
  u16 xh16[8][4];
#pragma unroll
  for (int k = 0; k < 8; ++k) {
    int h = hb * 8 + k;
    float acc[4] = {bias[0], bias[1], bias[2], bias[3]};
#pragma unroll
    for (int dh = 0; dh < 3; ++dh) {
#pragma unroll
      for (int dw = -1; dw <= 1; ++dw) {
        int ww = w + dw;
        if (ww < 0 || ww > 31) continue;
        const float* p = &Ls[h + dh][ww][c4 * 4];
        int kb = dh * 3 + (dw + 1);
#pragma unroll
        for (int j = 0; j < 4; ++j) acc[j] = fmaf(p[j], wt[j][kb], acc[j]);
      }
    }
    float s4[4];
#pragma unroll
    for (int j = 0; j < 4; ++j) { float v = acc[j]; s4[j] = v / (1.f + expf(-v)); }
    if (isx) {
#pragma unroll
      for (int j = 0; j < 4; ++j) xh16[k][j] = f2h(s4[j]);
    } else {
      size_t row = (size_t)b * 1024 + (h0 + h) * 32 + w;
      u16 hv[4] = {f2h(s4[0]), f2h(s4[1]), f2h(s4[2]), f2h(s4[3])};
      uint2 hp = make_uint2((u32)hv[0] | ((u32)hv[1] << 16), (u32)hv[2] | ((u32)hv[3] << 16));
      int c = c0 + c4 * 4;
      if (c < DI + DS) *(uint2*)&Bh[row * DS + (c - DI)] = hp;
      else             *(uint2*)&Chh[row * DS + (c - DI - DS)] = hp;
    }
  }
  if (isx) {
    __syncthreads();
    u16* Ls2 = (u16*)Ls;
#pragma unroll
    for (int k = 0; k < 8; ++k) {
      int pos = (hb * 8 + k) * 32 + w;
#pragma unroll
      for (int j = 0; j < 4; ++j)
        Ls2[(c4 * 4 + j) * 512 + pos] = xh16[k][j];
    }
    __syncthreads();
    const int hh = c0 >> 6;
    const int pb = c0 & 63;
#pragma unroll
    for (int i = 0; i < 4; ++i) {
      int cid = i * 256 + t;
      int pl = cid >> 6, rem = cid & 63;
      int jbl = rem >> 3, slot = rem & 7;
      int labs = h0 * 32 + jbl * 64;
      size_t tile = ((size_t)(b * 4 + (labs >> 8)) * NH + hh) * 4 + ((labs >> 6) & 3);
      *(uint4*)((char*)XTh + tile * 8192 + SWZ(pb + pl, slot)) =
          *(const uint4*)&Ls2[pl * 512 + jbl * 64 + slot * 8];
    }
  }
}

// stage one pre-swizzled 8KB XT tile into LDS via linear DMA
#define STAGE_XT(tileByte) do {                                                                   \
  _Pragma("unroll")                                                                               \
  for (int i_ = 0; i_ < 2; ++i_) {                                                                \
    int S_ = i_ * 256 + t;                                                                        \
    __builtin_amdgcn_global_load_lds(                                                             \
        (const __attribute__((address_space(1))) u32*)((const char*)XTh + (tileByte) + S_ * 16),  \
        (__attribute__((address_space(3))) u32*)((char*)Xh_t + S_ * 16), 16, 0, 0);               \
  }                                                                                               \
} while (0)

// ---------------- K5: chunk states via MFMA; fp16 output ----------------
__global__ __launch_bounds__(256) void k_states(
    const u16* __restrict__ XTh,
    const u16* __restrict__ Bh,
    const float* __restrict__ dt, const float* __restrict__ dAcs,
    u16* __restrict__ st16)
{
  __shared__ u16 bpackB[64 * 65];
  __shared__ u16 BTh_t[4096];
  __shared__ u16 Xh_t[4096];
  __shared__ float wall[256];
  const int bc = blockIdx.x;
  const int hh = blockIdx.y;
  const int t  = threadIdx.x;
  const int lane = t & 63, w = t >> 6;
  const int mlo = lane & 15, gg = lane >> 4;
  const int r = t >> 2, q = (t & 3) * 16;
  const size_t base = (size_t)bc * 256;
  const float last = dAcs[(base + 255) * NH + hh];
  wall[t] = __expf(last - dAcs[(base + t) * NH + hh]) * dt[(base + t) * NH + hh];
  f32x4 acc[4];
#pragma unroll
  for (int i = 0; i < 4; ++i) acc[i] = (f32x4){0.f, 0.f, 0.f, 0.f};
  for (int jt = 0; jt < 4; ++jt) {
    const int j0 = jt * 64;
    __syncthreads();
    STAGE_XT(((size_t)(bc * NH + hh) * 4 + jt) * 8192);
    {
      const u16* bhp = &Bh[(size_t)(base + j0 + r) * DS + q];
      U4 H0, H1;
      H0.v = *(const uint4*)bhp; H1.v = *(const uint4*)(bhp + 8);
#pragma unroll
      for (int k = 0; k < 8; ++k) {
        bpackB[r * 65 + q + k]     = H0.s[k];
        bpackB[r * 65 + q + 8 + k] = H1.s[k];
      }
    }
    __syncthreads();
#pragma unroll
    for (int c = 0; c < 2; ++c) {
      U4 BH;
#pragma unroll
      for (int jj = 0; jj < 8; ++jj) {
        int j = q + c * 8 + jj;
        BH.s[jj] = f2h(h2f(bpackB[j * 65 + r]) * wall[j0 + j]);
      }
      *(uint4*)((char*)BTh_t + SWZ(r, (q >> 3) + c)) = BH.v;
    }
    __syncthreads();
#pragma unroll
    for (int s = 0; s < 2; ++s) {
      f16x8 fah = *(const f16x8*)((const char*)Xh_t + SWZ(w * 16 + mlo, s * 4 + gg));
#pragma unroll
      for (int nf = 0; nf < 4; ++nf) {
        f16x8 fbh = *(const f16x8*)((const char*)BTh_t + SWZ(nf * 16 + mlo, s * 4 + gg));
        acc[nf] = __builtin_amdgcn_mfma_f32_16x16x32_f16(fah, fbh, acc[nf], 0, 0, 0);
      }
    }
  }
  const size_t sb = ((size_t)(bc * NH + hh)) << 12;
#pragma unroll
  for (int nf = 0; nf < 4; ++nf)
#pragma unroll
    for (int reg = 0; reg < 4; ++reg) {
      int p = w * 16 + (lane >> 4) * 4 + reg;
      int n = nf * 16 + mlo;
      st16[sb + (size_t)p * 64 + n] = f2h(acc[nf][reg]);
    }
}

// ---------------- K7: y = intra + inter + D*x; inline inter-chunk scan; i-tile PAIR per block ----------------
__global__ __launch_bounds__(256) void k_y(
    const u16* __restrict__ XTh,
    const u16* __restrict__ Chg, const u16* __restrict__ Bhg,
    const float* __restrict__ dtp, const float* __restrict__ dAcs,
    const u16* __restrict__ st16, const float* __restrict__ cdec,
    const float* __restrict__ Dp,
    u16* __restrict__ y)
{
  __shared__ u16 Pb_t[4096];
  __shared__ u16 Xh_t[4096];
  __shared__ u16 att_t[4096];
  __shared__ float dAc_s[256], dt_s[256], ei_s[128];
  const int bc = blockIdx.x;
  const int hh = blockIdx.y;
  const int z  = blockIdx.z;
  const int it0 = z * 2;
  const int t  = threadIdx.x;
  const int lane = t & 63, w = t >> 6;
  const int mlo = lane & 15, gg = lane >> 4;
  const int r = t >> 2, q = (t & 3) * 16;
  const int slot0 = q >> 3;
  const size_t base = (size_t)bc * 256;
  {
    float da = dAcs[(base + t) * NH + hh];
    dAc_s[t] = da;
    dt_s[t]  = dtp[(base + t) * NH + hh];
    if (t < 128) ei_s[t] = __expf(dAcs[(base + z * 128 + t) * NH + hh]);
  }
  // inline inter-chunk scan: prev for this (bc,hh), 16 elems/thread
  {
    const int b = bc >> 2, cchunk = bc & 3;
    float carry[16];
#pragma unroll
    for (int k = 0; k < 16; ++k) carry[k] = 0.f;
    for (int c2 = 0; c2 < cchunk; ++c2) {            // uniform runtime loop
      float dec = cdec[(b * 4 + c2) * NH + hh];
      const u16* sp = &st16[(((size_t)((b * 4 + c2) * NH + hh)) << 12) + (size_t)r * 64 + q];
      U4 S0, S1;
      S0.v = *(const uint4*)sp; S1.v = *(const uint4*)(sp + 8);
#pragma unroll
      for (int k = 0; k < 8; ++k) {
        carry[k]     = carry[k]     * dec + h2f(S0.s[k]);
        carry[k + 8] = carry[k + 8] * dec + h2f(S1.s[k]);
      }
    }
    U4 H0, H1;
#pragma unroll
    for (int k = 0; k < 8; ++k) { H0.s[k] = f2h(carry[k]); H1.s[k] = f2h(carry[k + 8]); }
    *(uint4*)((char*)Pb_t + SWZ(r, slot0))     = H0.v;
    *(uint4*)((char*)Pb_t + SWZ(r, slot0 + 1)) = H1.v;
  }
  __syncthreads();
  f16x8 fc[2][2];
#pragma unroll
  for (int iti = 0; iti < 2; ++iti)
#pragma unroll
    for (int s = 0; s < 2; ++s)
      fc[iti][s] = *(const f16x8*)&Chg[(size_t)(base + (it0 + iti) * 64 + w * 16 + mlo) * DS +
                                       (s * 4 + gg) * 8];
  f32x4 accy[2][4];
#pragma unroll
  for (int i = 0; i < 2; ++i)
#pragma unroll
    for (int j = 0; j < 4; ++j) accy[i][j] = (f32x4){0.f, 0.f, 0.f, 0.f};
#pragma unroll
  for (int s = 0; s < 2; ++s)
#pragma unroll
    for (int pf = 0; pf < 4; ++pf) {
      f16x8 fph = *(const f16x8*)((const char*)Pb_t + SWZ(pf * 16 + mlo, s * 4 + gg));
#pragma unroll
      for (int iti = 0; iti < 2; ++iti)
        accy[iti][pf] = __builtin_amdgcn_mfma_f32_16x16x32_f16(fc[iti][s], fph, accy[iti][pf], 0, 0, 0);
    }
  const int ilb = w * 16 + (lane >> 4) * 4;
#pragma unroll
  for (int iti = 0; iti < 2; ++iti)
#pragma unroll
    for (int pf = 0; pf < 4; ++pf)
#pragma unroll
      for (int reg = 0; reg < 4; ++reg)
        accy[iti][pf][reg] *= ei_s[iti * 64 + ilb + reg];

  u32 xdv[2][8];
  for (int jt = 0; jt <= it0 + 1; ++jt) {
    __syncthreads();
    STAGE_XT(((size_t)(bc * NH + hh) * 4 + jt) * 8192);
    {
      const u16* bh = &Bhg[(size_t)(base + jt * 64 + r) * DS + q];
      U4 V0, V1;
      V0.v = *(const uint4*)bh; V1.v = *(const uint4*)(bh + 8);
      float wj = dt_s[jt * 64 + r];
#pragma unroll
      for (int k = 0; k < 8; ++k) {
        V0.s[k] = f2h(h2f(V0.s[k]) * wj);
        V1.s[k] = f2h(h2f(V1.s[k]) * wj);
      }
      *(uint4*)((char*)Pb_t + SWZ(r, slot0))     = V0.v;
      *(uint4*)((char*)Pb_t + SWZ(r, slot0 + 1)) = V1.v;
    }
    __syncthreads();
#pragma unroll
    for (int iti = 0; iti < 2; ++iti) {
      if (jt == it0 + iti) {
#pragma unroll
        for (int pf = 0; pf < 4; ++pf)
#pragma unroll
          for (int rp = 0; rp < 2; ++rp) {
            int j0l = ilb + rp * 2;
            u16 a = *(const u16*)((const char*)Xh_t + SWZ(pf * 16 + mlo, j0l >> 3) + (j0l & 7) * 2);
            u16 b2 = *(const u16*)((const char*)Xh_t + SWZ(pf * 16 + mlo, (j0l + 1) >> 3) + ((j0l + 1) & 7) * 2);
            xdv[iti][pf * 2 + rp] = (u32)a | ((u32)b2 << 16);
          }
      }
    }
#pragma unroll
    for (int iti = 0; iti < 2; ++iti) {
      const int ita = it0 + iti;
      if (jt > ita) continue;
      f32x4 g[4];
#pragma unroll
      for (int i = 0; i < 4; ++i) g[i] = (f32x4){0.f, 0.f, 0.f, 0.f};
#pragma unroll
      for (int s = 0; s < 2; ++s)
#pragma unroll
        for (int jf = 0; jf < 4; ++jf) {
          f16x8 fbh = *(const f16x8*)((const char*)Pb_t + SWZ(jf * 16 + mlo, s * 4 + gg));
          g[jf] = __builtin_amdgcn_mfma_f32_16x16x32_f16(fc[iti][s], fbh, g[jf], 0, 0, 0);
        }
#pragma unroll
      for (int jf = 0; jf < 4; ++jf)
#pragma unroll
        for (int reg = 0; reg < 4; ++reg) {
          int il = ita * 64 + ilb + reg;
          int jl = jt * 64 + jf * 16 + mlo;
          float av = (jl <= il) ? g[jf][reg] * __expf(dAc_s[il] - dAc_s[jl]) : 0.f;
          *(u16*)((char*)att_t + SWZ(il & 63, (jl & 63) >> 3) + (jl & 7) * 2) = f2h(av);
        }
#pragma unroll
      for (int s = 0; s < 2; ++s) {
        f16x8 fa = *(const f16x8*)((const char*)att_t + SWZ(w * 16 + mlo, s * 4 + gg));
#pragma unroll
        for (int pf = 0; pf < 4; ++pf) {
          f16x8 fxh = *(const f16x8*)((const char*)Xh_t + SWZ(pf * 16 + mlo, s * 4 + gg));
          accy[iti][pf] = __builtin_amdgcn_mfma_f32_16x16x32_f16(fa, fxh, accy[iti][pf], 0, 0, 0);
        }
      }
    }
  }
  const float Dh = Dp[hh];
#pragma unroll
  for (int iti = 0; iti < 2; ++iti)
#pragma unroll
    for (int pf = 0; pf < 4; ++pf)
#pragma unroll
      for (int reg = 0; reg < 4; ++reg) {
        size_t row = base + (it0 + iti) * 64 + ilb + reg;
        int col = hh * HD + pf * 16 + mlo;
        u32 pk = xdv[iti][pf * 2 + (reg >> 1)];
        u16 xv = (reg & 1) ? (u16)(pk >> 16) : (u16)pk;
        y[row * DI + col] = f2h(accy[iti][pf][reg] + Dh * h2f(xv));
      }
}

extern "C" void kernel_launch(void* const* d_in, const int* in_sizes, int n_in,
                              void* d_out, int out_size, void* d_ws, size_t ws_size,
                              hipStream_t stream)
{
  const float* u    = (const float*)d_in[0];
  const float* ipw  = (const float*)d_in[1];
  const float* cw   = (const float*)d_in[2];
  const float* cb   = (const float*)d_in[3];
  const float* dtb  = (const float*)d_in[4];
  const float* Alog = (const float*)d_in[5];
  const float* Dp   = (const float*)d_in[6];
  const float* nw   = (const float*)d_in[7];
  const float* nb   = (const float*)d_in[8];
  const float* opw  = (const float*)d_in[9];
  float* out = (float*)d_out;

  float* ws = (float*)d_ws;
  size_t off = 0;
  u16*   z16     = (u16*)(ws + off); off += (size_t)B_ * L_ * DI / 2;
  u16*   xBC16   = (u16*)(ws + off); off += (size_t)B_ * L_ * CONVD / 2;
  float* dt_buf  = ws + off; off += (size_t)B_ * L_ * NH;
  float* x_buf   = ws + off; off += (size_t)B_ * L_ * DI;     // alias space only
  u16*   y16     = (u16*)(ws + off); off += (size_t)B_ * L_ * DI / 2;
  u16*   Bh_buf  = (u16*)(ws + off); off += (size_t)B_ * L_ * DS / 2;
  u16*   Ch_buf  = (u16*)(ws + off); off += (size_t)B_ * L_ * DS / 2;
  float* dAcs    = ws + off; off += (size_t)B_ * L_ * NH;
  float* cdec    = ws + off; off += (size_t)B_ * NCH * NH;
  u16*   st16    = (u16*)(ws + off); off += (size_t)B_ * NCH * NH * HD * DS / 2;
  u16*   Woh     = (u16*)(ws + off); off += (size_t)DM * DI / 2;
  u16*   XTh_buf = (u16*)(ws + off); off += (size_t)B_ * NCH * NH * 4 * 4096 / 2;

  // aliases inside x_buf (dead/live windows don't overlap)
  u16* Ah = (u16*)x_buf;
  u16* Whip = Ah + (size_t)B_ * L_ * DM;

  hipLaunchKernelGGL(k_prep, dim3(3216), dim3(256), 0, stream,
                     u, ipw, opw, dtb, Alog, Ah, Whip, Woh, dt_buf, dAcs, cdec);
  hipLaunchKernelGGL(k_gemm1, dim3(128, 13), dim3(256), 0, stream,
                     Ah, Whip, z16, xBC16);
  hipLaunchKernelGGL(k_conv, dim3(56, 2, 16), dim3(256), 0, stream,
                     xBC16, cw, cb, XTh_buf, Bh_buf, Ch_buf);
  hipLaunchKernelGGL(k_states, dim3(64, 12), dim3(256), 0, stream,
                     XTh_buf, Bh_buf, dt_buf, dAcs, st16);
  hipLaunchKernelGGL(k_y, dim3(64, 12, 2), dim3(256), 0, stream,
                     XTh_buf, Ch_buf, Bh_buf, dt_buf, dAcs, st16, cdec, Dp, y16);
  hipLaunchKernelGGL(k_gemm2n, dim3(128, 3), dim3(256), 0, stream,
                     y16, z16, nw, nb, Woh, out);
}

// Round 24
// 187.496 us; speedup vs baseline: 1.0294x; 1.0294x over previous
//
#include <hip/hip_runtime.h>
#include <hip/hip_bf16.h>

#define B_    16
#define L_    1024
#define DM    384
#define DIP   1676
#define NIP   1664
#define DI    768
#define CONVD 896
#define NH    12
#define HD    64
#define DS    64
#define NCH   4
#define CH    256
#define EPS_  1e-5f

typedef unsigned short u16;
typedef unsigned int   u32;
typedef __attribute__((ext_vector_type(8))) _Float16 f16x8;
typedef __attribute__((ext_vector_type(4))) float f32x4;

union U4 { uint4 v; u16 s[8]; };

#define SWZ(row, slot) (((row) << 7) + ((((slot) ^ ((row) & 7)) & 7) << 4))

__device__ __forceinline__ u16 f2h(float v) { return __builtin_bit_cast(u16, (_Float16)v); }
__device__ __forceinline__ float h2f(u16 h) { return (float)__builtin_bit_cast(_Float16, h); }

// ---------------- K_prep: fused cvtA + cvtWh(ipw) + cvtWh(opw) + dtp ----------------
__global__ __launch_bounds__(256) void k_prep(
    const float* __restrict__ u, const float* __restrict__ ipw,
    const float* __restrict__ opw,
    const float* __restrict__ dtb, const float* __restrict__ A_log,
    u16* __restrict__ Ah, u16* __restrict__ Whip, u16* __restrict__ Woh,
    float* __restrict__ dt, float* __restrict__ dAcs, float* __restrict__ cdecay)
{
  __shared__ float smem[32 * 129 + 8];
  const int bid = blockIdx.x;
  const int t = threadIdx.x;
  if (bid < 1536) {
    float (*Ls)[129] = (float(*)[129])smem;
    const int l0 = (bid & 7) * 128;
    const int k0 = ((bid >> 3) % 12) * 32;
    const int b  = bid / 96;
#pragma unroll
    for (int r = 0; r < 4; ++r) {
      int idx = r * 256 + t;
      int kk = idx >> 5, q = idx & 31;
      float4 v = *(const float4*)&u[((size_t)(b * DM + k0 + kk)) * L_ + l0 + q * 4];
      Ls[kk][q * 4 + 0] = v.x; Ls[kk][q * 4 + 1] = v.y;
      Ls[kk][q * 4 + 2] = v.z; Ls[kk][q * 4 + 3] = v.w;
    }
    __syncthreads();
#pragma unroll
    for (int it = 0; it < 2; ++it) {
      int task = it * 256 + t;
      int l = task >> 2, kq = (task & 3) * 8;
      u32 hw[4];
#pragma unroll
      for (int j = 0; j < 4; ++j) {
        u16 h0 = f2h(Ls[kq + 2 * j + 0][l]);
        u16 h1 = f2h(Ls[kq + 2 * j + 1][l]);
        hw[j] = (u32)h0 | ((u32)h1 << 16);
      }
      size_t off = ((size_t)(b * L_ + l0 + l)) * DM + k0 + kq;
      *(uint4*)&Ah[off] = make_uint4(hw[0], hw[1], hw[2], hw[3]);
    }
  } else if (bid < 2160) {
    int i = (bid - 1536) * 256 + t;
    if (i < NIP * DM / 4) {
      int e = i * 4;
      float4 v = *(const float4*)&ipw[e];
      u16 h[4] = {f2h(v.x), f2h(v.y), f2h(v.z), f2h(v.w)};
      *(uint2*)&Whip[e] = make_uint2((u32)h[0] | ((u32)h[1] << 16), (u32)h[2] | ((u32)h[3] << 16));
    }
  } else if (bid < 2448) {
    int i = (bid - 2160) * 256 + t;
    if (i < DM * DI / 4) {
      int e = i * 4;
      float4 v = *(const float4*)&opw[e];
      u16 h[4] = {f2h(v.x), f2h(v.y), f2h(v.z), f2h(v.w)};
      *(uint2*)&Woh[e] = make_uint2((u32)h[0] | ((u32)h[1] << 16), (u32)h[2] | ((u32)h[3] << 16));
    }
  } else {
    float* wdt = smem;
    float* ws4 = smem + DM;
    const int bb = bid - 2448;
    const int bc = bb & 63;
    const int h  = bb >> 6;
    const int b  = bc >> 2, l0 = (bc & 3) * 256;
    const int lane = t & 63, w = t >> 6;
    for (int i = t; i < DM; i += 256) wdt[i] = ipw[(size_t)(NIP + h) * DM + i];
    __syncthreads();
    const float* ub = u + (size_t)b * DM * L_ + l0 + t;
    float acc = 0.f;
#pragma unroll 8
    for (int k = 0; k < DM; ++k)
      acc = fmaf(ub[(size_t)k * L_], wdt[k], acc);
    const size_t row = (size_t)bc * 256 + t;
    float logit = acc + dtb[h];
    float dtv = (logit > 20.f) ? logit : log1pf(expf(logit));
    dt[row * NH + h] = dtv;
    float xv = dtv * (-expf(A_log[h]));
#pragma unroll
    for (int off = 1; off < 64; off <<= 1) {
      float y = __shfl_up(xv, off, 64);
      if (lane >= off) xv += y;
    }
    if (lane == 63) ws4[w] = xv;
    __syncthreads();
    float add = 0.f;
#pragma unroll
    for (int i = 0; i < 4; ++i) if (i < w) add += ws4[i];
    xv += add;
    dAcs[row * NH + h] = xv;
    if (t == 255) cdecay[bc * NH + h] = expf(xv);
  }
}

// 2-stream staging of one 128x32 u16 K-tile set (stride KS) into buffer `bufbase`
#define STAGE2S(bufbase, k0, KS) do {                                                           \
  _Pragma("unroll")                                                                             \
  for (int i_ = 0; i_ < 2; ++i_) {                                                              \
    int S_ = i_ * 256 + t;                                                                      \
    int m_ = S_ >> 2;                                                                           \
    int g_ = (S_ ^ (m_ >> 1)) & 3;                                                              \
    size_t goff_ = (size_t)m_ * (KS) + (k0) + g_ * 8;                                           \
    __builtin_amdgcn_global_load_lds((const __attribute__((address_space(1))) u32*)(g0 + goff_),\
        (__attribute__((address_space(3))) u32*)(lds + (bufbase) + S_ * 8), 16, 0, 0);          \
    __builtin_amdgcn_global_load_lds((const __attribute__((address_space(1))) u32*)(g2 + goff_),\
        (__attribute__((address_space(3))) u32*)(lds + (bufbase) + 4096 + S_ * 8), 16, 0, 0);   \
  }                                                                                             \
} while (0)

// ---------------- fp16 MFMA GEMM: in_proj — 128x128, 2-buffer counted-vmcnt + XCD swizzle ----------------
__global__ __launch_bounds__(256) void k_gemm1(
    const u16* __restrict__ Ah,
    const u16* __restrict__ Wh,
    u16* __restrict__ z, u16* __restrict__ xBC)
{
  __shared__ u16 lds[16384];
  const int t = threadIdx.x;
  const int lane = t & 63, wid = t >> 6;
  const int wr = wid >> 1, wc = wid & 1;
  const int gg = lane >> 4, mlo = lane & 15;
  const int xs = (blockIdx.x & 7) * 16 + (blockIdx.x >> 3);
  const int m0 = xs * 128, n0 = blockIdx.y * 128;
  f32x4 acc[4][4];
#pragma unroll
  for (int i = 0; i < 4; ++i)
#pragma unroll
    for (int j = 0; j < 4; ++j) acc[i][j] = (f32x4){0.f, 0.f, 0.f, 0.f};
  const u16* g0 = Ah + (size_t)m0 * DM;
  const u16* g2 = Wh + (size_t)n0 * DM;
  const int NT = DM / 32;
  STAGE2S(0, 0, DM);
  int cur = 0;
  for (int kt = 0; kt < NT; ++kt) {
    int ks = kt + 1; if (ks > NT - 1) ks = NT - 1;
    STAGE2S((cur ^ 1) * 8192, ks * 32, DM);
    asm volatile("s_waitcnt vmcnt(4)" ::: "memory");
    __builtin_amdgcn_s_barrier();
    const char* ldsb = (const char*)lds + cur * 16384;
    f16x8 fa[4], fb[4];
#pragma unroll
    for (int mf = 0; mf < 4; ++mf) {
      int m = wr * 64 + mf * 16 + mlo;
      int off = m * 64 + (((gg ^ (m >> 1)) & 3) << 4);
      fa[mf]  = *(const f16x8*)(ldsb + off);
    }
#pragma unroll
    for (int nf = 0; nf < 4; ++nf) {
      int n = wc * 64 + nf * 16 + mlo;
      int off = n * 64 + (((gg ^ (n >> 1)) & 3) << 4);
      fb[nf]  = *(const f16x8*)(ldsb + 8192 + off);
    }
#pragma unroll
    for (int mf = 0; mf < 4; ++mf)
#pragma unroll
      for (int nf = 0; nf < 4; ++nf)
        acc[mf][nf] = __builtin_amdgcn_mfma_f32_16x16x32_f16(fa[mf], fb[nf], acc[mf][nf], 0, 0, 0);
    __builtin_amdgcn_s_barrier();
    cur ^= 1;
  }
  const int rb = m0 + wr * 64 + (lane >> 4) * 4;
  const int cb = n0 + wc * 64 + mlo;
#pragma unroll
  for (int mf = 0; mf < 4; ++mf)
#pragma unroll
    for (int nf = 0; nf < 4; ++nf) {
      int col = cb + nf * 16;
#pragma unroll
      for (int r = 0; r < 4; ++r) {
        int row = rb + mf * 16 + r;
        float v = acc[mf][nf][r];
        if (col < DI) z[(size_t)row * DI + col] = f2h(v);
        else xBC[(size_t)row * CONVD + (col - DI)] = f2h(v);
      }
    }
}

// ---------------- fp16 MFMA GEMM: out_proj — single x single, counted-vmcnt 2-buffer + XCD swizzle ----------------
__global__ __launch_bounds__(256) void k_gemm2(
    const u16* __restrict__ Ah,
    const u16* __restrict__ Bh,
    float* __restrict__ out)
{
  __shared__ u16 lds[16384];
  const int t = threadIdx.x;
  const int lane = t & 63, wid = t >> 6;
  const int wr = wid >> 1, wc = wid & 1;
  const int gg = lane >> 4, mlo = lane & 15;
  const int xs = (blockIdx.x & 7) * 16 + (blockIdx.x >> 3);
  const int m0 = xs * 128, n0 = blockIdx.y * 128;
  f32x4 acc[4][4];
#pragma unroll
  for (int i = 0; i < 4; ++i)
#pragma unroll
    for (int j = 0; j < 4; ++j) acc[i][j] = (f32x4){0.f, 0.f, 0.f, 0.f};
  const u16* g0 = Ah + (size_t)m0 * DI;
  const u16* g2 = Bh + (size_t)n0 * DI;
  const int NT = DI / 32;
  STAGE2S(0, 0, DI);
  int cur = 0;
  for (int kt = 0; kt < NT; ++kt) {
    int ks = kt + 1; if (ks > NT - 1) ks = NT - 1;
    STAGE2S((cur ^ 1) * 8192, ks * 32, DI);
    asm volatile("s_waitcnt vmcnt(4)" ::: "memory");
    __builtin_amdgcn_s_barrier();
    const char* ldsb = (const char*)lds + cur * 16384;
    f16x8 fa[4], fb[4];
#pragma unroll
    for (int mf = 0; mf < 4; ++mf) {
      int m = wr * 64 + mf * 16 + mlo;
      int off = m * 64 + (((gg ^ (m >> 1)) & 3) << 4);
      fa[mf]  = *(const f16x8*)(ldsb + off);
    }
#pragma unroll
    for (int nf = 0; nf < 4; ++nf) {
      int n = wc * 64 + nf * 16 + mlo;
      int off = n * 64 + (((gg ^ (n >> 1)) & 3) << 4);
      fb[nf]  = *(const f16x8*)(ldsb + 8192 + off);
    }
#pragma unroll
    for (int mf = 0; mf < 4; ++mf)
#pragma unroll
      for (int nf = 0; nf < 4; ++nf)
        acc[mf][nf] = __builtin_amdgcn_mfma_f32_16x16x32_f16(fa[mf], fb[nf], acc[mf][nf], 0, 0, 0);
    __builtin_amdgcn_s_barrier();
    cur ^= 1;
  }
  const int rb = m0 + wr * 64 + (lane >> 4) * 4;
  const int cb = n0 + wc * 64 + mlo;
#pragma unroll
  for (int mf = 0; mf < 4; ++mf)
#pragma unroll
    for (int nf = 0; nf < 4; ++nf) {
      int col = cb + nf * 16;
#pragma unroll
      for (int r = 0; r < 4; ++r) {
        int row = rb + mf * 16 + r;
        int b = row >> 10, l = row & 1023;
        out[((size_t)(b * DM + col)) * L_ + l] = acc[mf][nf][r];
      }
    }
}

// ---------------- K2: depthwise conv; x-channels -> pre-swizzled XT fp16 tiles; B/C fp16 ----------------
#define CC 16
__global__ __launch_bounds__(256) void k_conv(
    const u16* __restrict__ xBC, const float* __restrict__ cw,
    const float* __restrict__ cb,
    u16* __restrict__ XTh,
    u16* __restrict__ Bh,
    u16* __restrict__ Chh)
{
  __shared__ float Ls[18][32][CC];
  const int t  = threadIdx.x;
  const int c0 = blockIdx.x * CC;
  const int h0 = blockIdx.y * 16;
  const int b  = blockIdx.z;
#pragma unroll
  for (int k = 0; k < 9; ++k) {
    int f = k * 256 + t;
    int fc4 = f & 3, fw = (f >> 2) & 31, fr = f >> 7;
    int h = h0 + fr - 1;
    U4 v; v.v = make_uint4(0, 0, 0, 0);
    if (h >= 0 && h < 32) {
      uint2 p = *(const uint2*)&xBC[((size_t)(b * 1024 + h * 32 + fw)) * CONVD + c0 + fc4 * 4];
      v.v.x = p.x; v.v.y = p.y;
    }
    Ls[fr][fw][fc4 * 4 + 0] = h2f(v.s[0]);
    Ls[fr][fw][fc4 * 4 + 1] = h2f(v.s[1]);
    Ls[fr][fw][fc4 * 4 + 2] = h2f(v.s[2]);
    Ls[fr][fw][fc4 * 4 + 3] = h2f(v.s[3]);
  }
  const int c4 = t & 3;
  const int w  = (t >> 2) & 31;
  const int hb = t >> 7;
  float wt[4][9];
  float bias[4];
#pragma unroll
  for (int j = 0; j < 4; ++j) {
    int c = c0 + c4 * 4 + j;
    bias[j] = cb[c];
#pragma unroll
    for (int kb = 0; kb < 9; ++kb) wt[j][kb] = cw[c * 9 + kb];
  }
  __syncthreads();
  const bool isx = (c0 < DI);
  u16 xh16[8][4];
#pragma unroll
  for (int k = 0; k < 8; ++k) {
    int h = hb * 8 + k;
    float acc[4] = {bias[0], bias[1], bias[2], bias[3]};
#pragma unroll
    for (int dh = 0; dh < 3; ++dh) {
#pragma unroll
      for (int dw = -1; dw <= 1; ++dw) {
        int ww = w + dw;
        if (ww < 0 || ww > 31) continue;
        const float* p = &Ls[h + dh][ww][c4 * 4];
        int kb = dh * 3 + (dw + 1);
#pragma unroll
        for (int j = 0; j < 4; ++j) acc[j] = fmaf(p[j], wt[j][kb], acc[j]);
      }
    }
    float s4[4];
#pragma unroll
    for (int j = 0; j < 4; ++j) { float v = acc[j]; s4[j] = v / (1.f + expf(-v)); }
    if (isx) {
#pragma unroll
      for (int j = 0; j < 4; ++j) xh16[k][j] = f2h(s4[j]);
    } else {
      size_t row = (size_t)b * 1024 + (h0 + h) * 32 + w;
      u16 hv[4] = {f2h(s4[0]), f2h(s4[1]), f2h(s4[2]), f2h(s4[3])};
      uint2 hp = make_uint2((u32)hv[0] | ((u32)hv[1] << 16), (u32)hv[2] | ((u32)hv[3] << 16));
      int c = c0 + c4 * 4;
      if (c < DI + DS) *(uint2*)&Bh[row * DS + (c - DI)] = hp;
      else             *(uint2*)&Chh[row * DS + (c - DI - DS)] = hp;
    }
  }
  if (isx) {
    __syncthreads();
    u16* Ls2 = (u16*)Ls;
#pragma unroll
    for (int k = 0; k < 8; ++k) {
      int pos = (hb * 8 + k) * 32 + w;
#pragma unroll
      for (int j = 0; j < 4; ++j)
        Ls2[(c4 * 4 + j) * 512 + pos] = xh16[k][j];
    }
    __syncthreads();
    const int hh = c0 >> 6;
    const int pb = c0 & 63;
#pragma unroll
    for (int i = 0; i < 4; ++i) {
      int cid = i * 256 + t;
      int pl = cid >> 6, rem = cid & 63;
      int jbl = rem >> 3, slot = rem & 7;
      int labs = h0 * 32 + jbl * 64;
      size_t tile = ((size_t)(b * 4 + (labs >> 8)) * NH + hh) * 4 + ((labs >> 6) & 3);
      *(uint4*)((char*)XTh + tile * 8192 + SWZ(pb + pl, slot)) =
          *(const uint4*)&Ls2[pl * 512 + jbl * 64 + slot * 8];
    }
  }
}

// stage one pre-swizzled 8KB XT tile into LDS via linear DMA
#define STAGE_XT(tileByte) do {                                                                   \
  _Pragma("unroll")                                                                               \
  for (int i_ = 0; i_ < 2; ++i_) {                                                                \
    int S_ = i_ * 256 + t;                                                                        \
    __builtin_amdgcn_global_load_lds(                                                             \
        (const __attribute__((address_space(1))) u32*)((const char*)XTh + (tileByte) + S_ * 16),  \
        (__attribute__((address_space(3))) u32*)((char*)Xh_t + S_ * 16), 16, 0, 0);               \
  }                                                                                               \
} while (0)

// ---------------- K5: chunk states via MFMA; fp16 output ----------------
__global__ __launch_bounds__(256) void k_states(
    const u16* __restrict__ XTh,
    const u16* __restrict__ Bh,
    const float* __restrict__ dt, const float* __restrict__ dAcs,
    u16* __restrict__ st16)
{
  __shared__ u16 bpackB[64 * 65];
  __shared__ u16 BTh_t[4096];
  __shared__ u16 Xh_t[4096];
  __shared__ float wall[256];
  const int bc = blockIdx.x;
  const int hh = blockIdx.y;
  const int t  = threadIdx.x;
  const int lane = t & 63, w = t >> 6;
  const int mlo = lane & 15, gg = lane >> 4;
  const int r = t >> 2, q = (t & 3) * 16;
  const size_t base = (size_t)bc * 256;
  const float last = dAcs[(base + 255) * NH + hh];
  wall[t] = __expf(last - dAcs[(base + t) * NH + hh]) * dt[(base + t) * NH + hh];
  f32x4 acc[4];
#pragma unroll
  for (int i = 0; i < 4; ++i) acc[i] = (f32x4){0.f, 0.f, 0.f, 0.f};
  for (int jt = 0; jt < 4; ++jt) {
    const int j0 = jt * 64;
    __syncthreads();
    STAGE_XT(((size_t)(bc * NH + hh) * 4 + jt) * 8192);
    {
      const u16* bhp = &Bh[(size_t)(base + j0 + r) * DS + q];
      U4 H0, H1;
      H0.v = *(const uint4*)bhp; H1.v = *(const uint4*)(bhp + 8);
#pragma unroll
      for (int k = 0; k < 8; ++k) {
        bpackB[r * 65 + q + k]     = H0.s[k];
        bpackB[r * 65 + q + 8 + k] = H1.s[k];
      }
    }
    __syncthreads();
#pragma unroll
    for (int c = 0; c < 2; ++c) {
      U4 BH;
#pragma unroll
      for (int jj = 0; jj < 8; ++jj) {
        int j = q + c * 8 + jj;
        BH.s[jj] = f2h(h2f(bpackB[j * 65 + r]) * wall[j0 + j]);
      }
      *(uint4*)((char*)BTh_t + SWZ(r, (q >> 3) + c)) = BH.v;
    }
    __syncthreads();
#pragma unroll
    for (int s = 0; s < 2; ++s) {
      f16x8 fah = *(const f16x8*)((const char*)Xh_t + SWZ(w * 16 + mlo, s * 4 + gg));
#pragma unroll
      for (int nf = 0; nf < 4; ++nf) {
        f16x8 fbh = *(const f16x8*)((const char*)BTh_t + SWZ(nf * 16 + mlo, s * 4 + gg));
        acc[nf] = __builtin_amdgcn_mfma_f32_16x16x32_f16(fah, fbh, acc[nf], 0, 0, 0);
      }
    }
  }
  const size_t sb = ((size_t)(bc * NH + hh)) << 12;
#pragma unroll
  for (int nf = 0; nf < 4; ++nf)
#pragma unroll
    for (int reg = 0; reg < 4; ++reg) {
      int p = w * 16 + (lane >> 4) * 4 + reg;
      int n = nf * 16 + mlo;
      st16[sb + (size_t)p * 64 + n] = f2h(acc[nf][reg]);
    }
}

// ---------------- K7: y = intra + inter + D*x; inline inter-chunk scan; i-tile PAIR per block ----------------
__global__ __launch_bounds__(256) void k_y(
    const u16* __restrict__ XTh,
    const u16* __restrict__ Chg, const u16* __restrict__ Bhg,
    const float* __restrict__ dtp, const float* __restrict__ dAcs,
    const u16* __restrict__ st16, const float* __restrict__ cdec,
    const float* __restrict__ Dp,
    u16* __restrict__ y)
{
  __shared__ u16 Pb_t[4096];
  __shared__ u16 Xh_t[4096];
  __shared__ u16 att_t[4096];
  __shared__ float dAc_s[256], dt_s[256], ei_s[128];
  const int bc = blockIdx.x;
  const int hh = blockIdx.y;
  const int z  = blockIdx.z;
  const int it0 = z * 2;
  const int t  = threadIdx.x;
  const int lane = t & 63, w = t >> 6;
  const int mlo = lane & 15, gg = lane >> 4;
  const int r = t >> 2, q = (t & 3) * 16;
  const int slot0 = q >> 3;
  const size_t base = (size_t)bc * 256;
  {
    float da = dAcs[(base + t) * NH + hh];
    dAc_s[t] = da;
    dt_s[t]  = dtp[(base + t) * NH + hh];
    if (t < 128) ei_s[t] = __expf(dAcs[(base + z * 128 + t) * NH + hh]);
  }
  // inline inter-chunk scan: prev for this (bc,hh), 16 elems/thread
  {
    const int b = bc >> 2, cchunk = bc & 3;
    float carry[16];
#pragma unroll
    for (int k = 0; k < 16; ++k) carry[k] = 0.f;
    for (int c2 = 0; c2 < cchunk; ++c2) {            // uniform runtime loop
      float dec = cdec[(b * 4 + c2) * NH + hh];
      const u16* sp = &st16[(((size_t)((b * 4 + c2) * NH + hh)) << 12) + (size_t)r * 64 + q];
      U4 S0, S1;
      S0.v = *(const uint4*)sp; S1.v = *(const uint4*)(sp + 8);
#pragma unroll
      for (int k = 0; k < 8; ++k) {
        carry[k]     = carry[k]     * dec + h2f(S0.s[k]);
        carry[k + 8] = carry[k + 8] * dec + h2f(S1.s[k]);
      }
    }
    U4 H0, H1;
#pragma unroll
    for (int k = 0; k < 8; ++k) { H0.s[k] = f2h(carry[k]); H1.s[k] = f2h(carry[k + 8]); }
    *(uint4*)((char*)Pb_t + SWZ(r, slot0))     = H0.v;
    *(uint4*)((char*)Pb_t + SWZ(r, slot0 + 1)) = H1.v;
  }
  __syncthreads();
  f16x8 fc[2][2];
#pragma unroll
  for (int iti = 0; iti < 2; ++iti)
#pragma unroll
    for (int s = 0; s < 2; ++s)
      fc[iti][s] = *(const f16x8*)&Chg[(size_t)(base + (it0 + iti) * 64 + w * 16 + mlo) * DS +
                                       (s * 4 + gg) * 8];
  f32x4 accy[2][4];
#pragma unroll
  for (int i = 0; i < 2; ++i)
#pragma unroll
    for (int j = 0; j < 4; ++j) accy[i][j] = (f32x4){0.f, 0.f, 0.f, 0.f};
#pragma unroll
  for (int s = 0; s < 2; ++s)
#pragma unroll
    for (int pf = 0; pf < 4; ++pf) {
      f16x8 fph = *(const f16x8*)((const char*)Pb_t + SWZ(pf * 16 + mlo, s * 4 + gg));
#pragma unroll
      for (int iti = 0; iti < 2; ++iti)
        accy[iti][pf] = __builtin_amdgcn_mfma_f32_16x16x32_f16(fc[iti][s], fph, accy[iti][pf], 0, 0, 0);
    }
  const int ilb = w * 16 + (lane >> 4) * 4;
#pragma unroll
  for (int iti = 0; iti < 2; ++iti)
#pragma unroll
    for (int pf = 0; pf < 4; ++pf)
#pragma unroll
      for (int reg = 0; reg < 4; ++reg)
        accy[iti][pf][reg] *= ei_s[iti * 64 + ilb + reg];

  u32 xdv[2][8];
  for (int jt = 0; jt <= it0 + 1; ++jt) {
    __syncthreads();
    STAGE_XT(((size_t)(bc * NH + hh) * 4 + jt) * 8192);
    {
      const u16* bh = &Bhg[(size_t)(base + jt * 64 + r) * DS + q];
      U4 V0, V1;
      V0.v = *(const uint4*)bh; V1.v = *(const uint4*)(bh + 8);
      float wj = dt_s[jt * 64 + r];
#pragma unroll
      for (int k = 0; k < 8; ++k) {
        V0.s[k] = f2h(h2f(V0.s[k]) * wj);
        V1.s[k] = f2h(h2f(V1.s[k]) * wj);
      }
      *(uint4*)((char*)Pb_t + SWZ(r, slot0))     = V0.v;
      *(uint4*)((char*)Pb_t + SWZ(r, slot0 + 1)) = V1.v;
    }
    __syncthreads();
#pragma unroll
    for (int iti = 0; iti < 2; ++iti) {
      if (jt == it0 + iti) {
#pragma unroll
        for (int pf = 0; pf < 4; ++pf)
#pragma unroll
          for (int rp = 0; rp < 2; ++rp) {
            int j0l = ilb + rp * 2;
            u16 a = *(const u16*)((const char*)Xh_t + SWZ(pf * 16 + mlo, j0l >> 3) + (j0l & 7) * 2);
            u16 b2 = *(const u16*)((const char*)Xh_t + SWZ(pf * 16 + mlo, (j0l + 1) >> 3) + ((j0l + 1) & 7) * 2);
            xdv[iti][pf * 2 + rp] = (u32)a | ((u32)b2 << 16);
          }
      }
    }
#pragma unroll
    for (int iti = 0; iti < 2; ++iti) {
      const int ita = it0 + iti;
      if (jt > ita) continue;
      f32x4 g[4];
#pragma unroll
      for (int i = 0; i < 4; ++i) g[i] = (f32x4){0.f, 0.f, 0.f, 0.f};
#pragma unroll
      for (int s = 0; s < 2; ++s)
#pragma unroll
        for (int jf = 0; jf < 4; ++jf) {
          f16x8 fbh = *(const f16x8*)((const char*)Pb_t + SWZ(jf * 16 + mlo, s * 4 + gg));
          g[jf] = __builtin_amdgcn_mfma_f32_16x16x32_f16(fc[iti][s], fbh, g[jf], 0, 0, 0);
        }
#pragma unroll
      for (int jf = 0; jf < 4; ++jf)
#pragma unroll
        for (int reg = 0; reg < 4; ++reg) {
          int il = ita * 64 + ilb + reg;
          int jl = jt * 64 + jf * 16 + mlo;
          float av = (jl <= il) ? g[jf][reg] * __expf(dAc_s[il] - dAc_s[jl]) : 0.f;
          *(u16*)((char*)att_t + SWZ(il & 63, (jl & 63) >> 3) + (jl & 7) * 2) = f2h(av);
        }
#pragma unroll
      for (int s = 0; s < 2; ++s) {
        f16x8 fa = *(const f16x8*)((const char*)att_t + SWZ(w * 16 + mlo, s * 4 + gg));
#pragma unroll
        for (int pf = 0; pf < 4; ++pf) {
          f16x8 fxh = *(const f16x8*)((const char*)Xh_t + SWZ(pf * 16 + mlo, s * 4 + gg));
          accy[iti][pf] = __builtin_amdgcn_mfma_f32_16x16x32_f16(fa, fxh, accy[iti][pf], 0, 0, 0);
        }
      }
    }
  }
  const float Dh = Dp[hh];
#pragma unroll
  for (int iti = 0; iti < 2; ++iti)
#pragma unroll
    for (int pf = 0; pf < 4; ++pf)
#pragma unroll
      for (int reg = 0; reg < 4; ++reg) {
        size_t row = base + (it0 + iti) * 64 + ilb + reg;
        int col = hh * HD + pf * 16 + mlo;
        u32 pk = xdv[iti][pf * 2 + (reg >> 1)];
        u16 xv = (reg & 1) ? (u16)(pk >> 16) : (u16)pk;
        y[row * DI + col] = f2h(accy[iti][pf][reg] + Dh * h2f(xv));
      }
}

// ---------------- K8: LayerNorm * z (both fp16 in) -> single fp16 y ----------------
__global__ __launch_bounds__(256) void k_norm(
    const u16* __restrict__ z, const float* __restrict__ nw,
    const float* __restrict__ nb, const u16* __restrict__ y,
    u16* __restrict__ yh)
{
  __shared__ float rs[4], rq[4];
  const size_t row = blockIdx.x;
  const int t = threadIdx.x;
  float v[3];
  float s = 0.f, sq = 0.f;
#pragma unroll
  for (int r = 0; r < 3; ++r) {
    v[r] = h2f(y[row * DI + r * 256 + t]);
    s += v[r];
    sq = fmaf(v[r], v[r], sq);
  }
#pragma unroll
  for (int off = 32; off > 0; off >>= 1) {
    s  += __shfl_down(s, off, 64);
    sq += __shfl_down(sq, off, 64);
  }
  const int wid = t >> 6, lane = t & 63;
  if (lane == 0) { rs[wid] = s; rq[wid] = sq; }
  __syncthreads();
  if (t == 0) {
    rs[0] = rs[0] + rs[1] + rs[2] + rs[3];
    rq[0] = rq[0] + rq[1] + rq[2] + rq[3];
  }
  __syncthreads();
  const float mu   = rs[0] * (1.f / DI);
  const float var  = rq[0] * (1.f / DI) - mu * mu;
  const float rstd = 1.f / sqrtf(var + EPS_);
#pragma unroll
  for (int r = 0; r < 3; ++r) {
    int d = r * 256 + t;
    float o = (v[r] - mu) * rstd * nw[d] + nb[d];
    float p = o * h2f(z[row * DI + d]);
    yh[row * DI + d] = f2h(p);
  }
}

extern "C" void kernel_launch(void* const* d_in, const int* in_sizes, int n_in,
                              void* d_out, int out_size, void* d_ws, size_t ws_size,
                              hipStream_t stream)
{
  const float* u    = (const float*)d_in[0];
  const float* ipw  = (const float*)d_in[1];
  const float* cw   = (const float*)d_in[2];
  const float* cb   = (const float*)d_in[3];
  const float* dtb  = (const float*)d_in[4];
  const float* Alog = (const float*)d_in[5];
  const float* Dp   = (const float*)d_in[6];
  const float* nw   = (const float*)d_in[7];
  const float* nb   = (const float*)d_in[8];
  const float* opw  = (const float*)d_in[9];
  float* out = (float*)d_out;

  float* ws = (float*)d_ws;
  size_t off = 0;
  u16*   z16     = (u16*)(ws + off); off += (size_t)B_ * L_ * DI / 2;
  u16*   xBC16   = (u16*)(ws + off); off += (size_t)B_ * L_ * CONVD / 2;
  float* dt_buf  = ws + off; off += (size_t)B_ * L_ * NH;
  float* x_buf   = ws + off; off += (size_t)B_ * L_ * DI;     // alias space only
  u16*   y16     = (u16*)(ws + off); off += (size_t)B_ * L_ * DI / 2;
  u16*   Bh_buf  = (u16*)(ws + off); off += (size_t)B_ * L_ * DS / 2;
  u16*   Ch_buf  = (u16*)(ws + off); off += (size_t)B_ * L_ * DS / 2;
  float* dAcs    = ws + off; off += (size_t)B_ * L_ * NH;
  float* cdec    = ws + off; off += (size_t)B_ * NCH * NH;
  u16*   st16    = (u16*)(ws + off); off += (size_t)B_ * NCH * NH * HD * DS / 2;
  u16*   Woh     = (u16*)(ws + off); off += (size_t)DM * DI / 2;
  u16*   XTh_buf = (u16*)(ws + off); off += (size_t)B_ * NCH * NH * 4 * 4096 / 2;

  // aliases inside x_buf (dead/live windows don't overlap)
  u16* Ah = (u16*)x_buf;
  u16* Whip = Ah + (size_t)B_ * L_ * DM;
  u16* yh = (u16*)x_buf;                         // single fp16 y for out_proj

  hipLaunchKernelGGL(k_prep, dim3(3216), dim3(256), 0, stream,
                     u, ipw, opw, dtb, Alog, Ah, Whip, Woh, dt_buf, dAcs, cdec);
  hipLaunchKernelGGL(k_gemm1, dim3(128, 13), dim3(256), 0, stream,
                     Ah, Whip, z16, xBC16);
  hipLaunchKernelGGL(k_conv, dim3(56, 2, 16), dim3(256), 0, stream,
                     xBC16, cw, cb, XTh_buf, Bh_buf, Ch_buf);
  hipLaunchKernelGGL(k_states, dim3(64, 12), dim3(256), 0, stream,
                     XTh_buf, Bh_buf, dt_buf, dAcs, st16);
  hipLaunchKernelGGL(k_y, dim3(64, 12, 2), dim3(256), 0, stream,
                     XTh_buf, Ch_buf, Bh_buf, dt_buf, dAcs, st16, cdec, Dp, y16);
  hipLaunchKernelGGL(k_norm, dim3(16384), dim3(256), 0, stream, z16, nw, nb, y16, yh);
  hipLaunchKernelGGL(k_gemm2, dim3(128, 3), dim3(256), 0, stream, yh, Woh, out);
}

// Round 25
// 187.482 us; speedup vs baseline: 1.0294x; 1.0001x over previous
//
#include <hip/hip_runtime.h>
#include <hip/hip_bf16.h>

#define B_    16
#define L_    1024
#define DM    384
#define DIP   1676
#define NIP   1664
#define DI    768
#define CONVD 896
#define NH    12
#define HD    64
#define DS    64
#define NCH   4
#define CH    256
#define EPS_  1e-5f

typedef unsigned short u16;
typedef unsigned int   u32;
typedef __attribute__((ext_vector_type(8))) _Float16 f16x8;
typedef __attribute__((ext_vector_type(4))) float f32x4;

union U4 { uint4 v; u16 s[8]; };

#define SWZ(row, slot) (((row) << 7) + ((((slot) ^ ((row) & 7)) & 7) << 4))

__device__ __forceinline__ u16 f2h(float v) { return __builtin_bit_cast(u16, (_Float16)v); }
__device__ __forceinline__ float h2f(u16 h) { return (float)__builtin_bit_cast(_Float16, h); }

// ---------------- K_prep: fused cvtA + cvtWh(ipw) + cvtWh(opw) + dtp ----------------
__global__ __launch_bounds__(256) void k_prep(
    const float* __restrict__ u, const float* __restrict__ ipw,
    const float* __restrict__ opw,
    const float* __restrict__ dtb, const float* __restrict__ A_log,
    u16* __restrict__ Ah, u16* __restrict__ Whip, u16* __restrict__ Woh,
    float* __restrict__ dt, float* __restrict__ dAcs, float* __restrict__ cdecay)
{
  __shared__ float smem[32 * 129 + 8];
  const int bid = blockIdx.x;
  const int t = threadIdx.x;
  if (bid < 1536) {
    float (*Ls)[129] = (float(*)[129])smem;
    const int l0 = (bid & 7) * 128;
    const int k0 = ((bid >> 3) % 12) * 32;
    const int b  = bid / 96;
#pragma unroll
    for (int r = 0; r < 4; ++r) {
      int idx = r * 256 + t;
      int kk = idx >> 5, q = idx & 31;
      float4 v = *(const float4*)&u[((size_t)(b * DM + k0 + kk)) * L_ + l0 + q * 4];
      Ls[kk][q * 4 + 0] = v.x; Ls[kk][q * 4 + 1] = v.y;
      Ls[kk][q * 4 + 2] = v.z; Ls[kk][q * 4 + 3] = v.w;
    }
    __syncthreads();
#pragma unroll
    for (int it = 0; it < 2; ++it) {
      int task = it * 256 + t;
      int l = task >> 2, kq = (task & 3) * 8;
      u32 hw[4];
#pragma unroll
      for (int j = 0; j < 4; ++j) {
        u16 h0 = f2h(Ls[kq + 2 * j + 0][l]);
        u16 h1 = f2h(Ls[kq + 2 * j + 1][l]);
        hw[j] = (u32)h0 | ((u32)h1 << 16);
      }
      size_t off = ((size_t)(b * L_ + l0 + l)) * DM + k0 + kq;
      *(uint4*)&Ah[off] = make_uint4(hw[0], hw[1], hw[2], hw[3]);
    }
  } else if (bid < 2160) {
    int i = (bid - 1536) * 256 + t;
    if (i < NIP * DM / 4) {
      int e = i * 4;
      float4 v = *(const float4*)&ipw[e];
      u16 h[4] = {f2h(v.x), f2h(v.y), f2h(v.z), f2h(v.w)};
      *(uint2*)&Whip[e] = make_uint2((u32)h[0] | ((u32)h[1] << 16), (u32)h[2] | ((u32)h[3] << 16));
    }
  } else if (bid < 2448) {
    int i = (bid - 2160) * 256 + t;
    if (i < DM * DI / 4) {
      int e = i * 4;
      float4 v = *(const float4*)&opw[e];
      u16 h[4] = {f2h(v.x), f2h(v.y), f2h(v.z), f2h(v.w)};
      *(uint2*)&Woh[e] = make_uint2((u32)h[0] | ((u32)h[1] << 16), (u32)h[2] | ((u32)h[3] << 16));
    }
  } else {
    float* wdt = smem;
    float* ws4 = smem + DM;
    const int bb = bid - 2448;
    const int bc = bb & 63;
    const int h  = bb >> 6;
    const int b  = bc >> 2, l0 = (bc & 3) * 256;
    const int lane = t & 63, w = t >> 6;
    for (int i = t; i < DM; i += 256) wdt[i] = ipw[(size_t)(NIP + h) * DM + i];
    __syncthreads();
    const float* ub = u + (size_t)b * DM * L_ + l0 + t;
    float acc = 0.f;
#pragma unroll 8
    for (int k = 0; k < DM; ++k)
      acc = fmaf(ub[(size_t)k * L_], wdt[k], acc);
    const size_t row = (size_t)bc * 256 + t;
    float logit = acc + dtb[h];
    float dtv = (logit > 20.f) ? logit : log1pf(expf(logit));
    dt[row * NH + h] = dtv;
    float xv = dtv * (-expf(A_log[h]));
#pragma unroll
    for (int off = 1; off < 64; off <<= 1) {
      float y = __shfl_up(xv, off, 64);
      if (lane >= off) xv += y;
    }
    if (lane == 63) ws4[w] = xv;
    __syncthreads();
    float add = 0.f;
#pragma unroll
    for (int i = 0; i < 4; ++i) if (i < w) add += ws4[i];
    xv += add;
    dAcs[row * NH + h] = xv;
    if (t == 255) cdecay[bc * NH + h] = expf(xv);
  }
}

// 2-stream staging of one 128x32 u16 K-tile set (stride KS) into buffer `bufbase`
#define STAGE2S(bufbase, k0, KS) do {                                                           \
  _Pragma("unroll")                                                                             \
  for (int i_ = 0; i_ < 2; ++i_) {                                                              \
    int S_ = i_ * 256 + t;                                                                      \
    int m_ = S_ >> 2;                                                                           \
    int g_ = (S_ ^ (m_ >> 1)) & 3;                                                              \
    size_t goff_ = (size_t)m_ * (KS) + (k0) + g_ * 8;                                           \
    __builtin_amdgcn_global_load_lds((const __attribute__((address_space(1))) u32*)(g0 + goff_),\
        (__attribute__((address_space(3))) u32*)(lds + (bufbase) + S_ * 8), 16, 0, 0);          \
    __builtin_amdgcn_global_load_lds((const __attribute__((address_space(1))) u32*)(g2 + goff_),\
        (__attribute__((address_space(3))) u32*)(lds + (bufbase) + 4096 + S_ * 8), 16, 0, 0);   \
  }                                                                                             \
} while (0)

// ---------------- fp16 MFMA GEMM: in_proj — 128x128, 2-buffer counted-vmcnt + XCD swizzle ----------------
__global__ __launch_bounds__(256) void k_gemm1(
    const u16* __restrict__ Ah,
    const u16* __restrict__ Wh,
    u16* __restrict__ z, u16* __restrict__ xBC)
{
  __shared__ u16 lds[16384];
  const int t = threadIdx.x;
  const int lane = t & 63, wid = t >> 6;
  const int wr = wid >> 1, wc = wid & 1;
  const int gg = lane >> 4, mlo = lane & 15;
  const int xs = (blockIdx.x & 7) * 16 + (blockIdx.x >> 3);
  const int m0 = xs * 128, n0 = blockIdx.y * 128;
  f32x4 acc[4][4];
#pragma unroll
  for (int i = 0; i < 4; ++i)
#pragma unroll
    for (int j = 0; j < 4; ++j) acc[i][j] = (f32x4){0.f, 0.f, 0.f, 0.f};
  const u16* g0 = Ah + (size_t)m0 * DM;
  const u16* g2 = Wh + (size_t)n0 * DM;
  const int NT = DM / 32;
  STAGE2S(0, 0, DM);
  int cur = 0;
  for (int kt = 0; kt < NT; ++kt) {
    int ks = kt + 1; if (ks > NT - 1) ks = NT - 1;
    STAGE2S((cur ^ 1) * 8192, ks * 32, DM);
    asm volatile("s_waitcnt vmcnt(4)" ::: "memory");
    __builtin_amdgcn_s_barrier();
    const char* ldsb = (const char*)lds + cur * 16384;
    f16x8 fa[4], fb[4];
#pragma unroll
    for (int mf = 0; mf < 4; ++mf) {
      int m = wr * 64 + mf * 16 + mlo;
      int off = m * 64 + (((gg ^ (m >> 1)) & 3) << 4);
      fa[mf]  = *(const f16x8*)(ldsb + off);
    }
#pragma unroll
    for (int nf = 0; nf < 4; ++nf) {
      int n = wc * 64 + nf * 16 + mlo;
      int off = n * 64 + (((gg ^ (n >> 1)) & 3) << 4);
      fb[nf]  = *(const f16x8*)(ldsb + 8192 + off);
    }
#pragma unroll
    for (int mf = 0; mf < 4; ++mf)
#pragma unroll
      for (int nf = 0; nf < 4; ++nf)
        acc[mf][nf] = __builtin_amdgcn_mfma_f32_16x16x32_f16(fa[mf], fb[nf], acc[mf][nf], 0, 0, 0);
    __builtin_amdgcn_s_barrier();
    cur ^= 1;
  }
  const int rb = m0 + wr * 64 + (lane >> 4) * 4;
  const int cb = n0 + wc * 64 + mlo;
#pragma unroll
  for (int mf = 0; mf < 4; ++mf)
#pragma unroll
    for (int nf = 0; nf < 4; ++nf) {
      int col = cb + nf * 16;
#pragma unroll
      for (int r = 0; r < 4; ++r) {
        int row = rb + mf * 16 + r;
        float v = acc[mf][nf][r];
        if (col < DI) z[(size_t)row * DI + col] = f2h(v);
        else xBC[(size_t)row * CONVD + (col - DI)] = f2h(v);
      }
    }
}

// ---------------- fp16 MFMA GEMM: out_proj — single x single, counted-vmcnt 2-buffer + XCD swizzle ----------------
__global__ __launch_bounds__(256) void k_gemm2(
    const u16* __restrict__ Ah,
    const u16* __restrict__ Bh,
    float* __restrict__ out)
{
  __shared__ u16 lds[16384];
  const int t = threadIdx.x;
  const int lane = t & 63, wid = t >> 6;
  const int wr = wid >> 1, wc = wid & 1;
  const int gg = lane >> 4, mlo = lane & 15;
  const int xs = (blockIdx.x & 7) * 16 + (blockIdx.x >> 3);
  const int m0 = xs * 128, n0 = blockIdx.y * 128;
  f32x4 acc[4][4];
#pragma unroll
  for (int i = 0; i < 4; ++i)
#pragma unroll
    for (int j = 0; j < 4; ++j) acc[i][j] = (f32x4){0.f, 0.f, 0.f, 0.f};
  const u16* g0 = Ah + (size_t)m0 * DI;
  const u16* g2 = Bh + (size_t)n0 * DI;
  const int NT = DI / 32;
  STAGE2S(0, 0, DI);
  int cur = 0;
  for (int kt = 0; kt < NT; ++kt) {
    int ks = kt + 1; if (ks > NT - 1) ks = NT - 1;
    STAGE2S((cur ^ 1) * 8192, ks * 32, DI);
    asm volatile("s_waitcnt vmcnt(4)" ::: "memory");
    __builtin_amdgcn_s_barrier();
    const char* ldsb = (const char*)lds + cur * 16384;
    f16x8 fa[4], fb[4];
#pragma unroll
    for (int mf = 0; mf < 4; ++mf) {
      int m = wr * 64 + mf * 16 + mlo;
      int off = m * 64 + (((gg ^ (m >> 1)) & 3) << 4);
      fa[mf]  = *(const f16x8*)(ldsb + off);
    }
#pragma unroll
    for (int nf = 0; nf < 4; ++nf) {
      int n = wc * 64 + nf * 16 + mlo;
      int off = n * 64 + (((gg ^ (n >> 1)) & 3) << 4);
      fb[nf]  = *(const f16x8*)(ldsb + 8192 + off);
    }
#pragma unroll
    for (int mf = 0; mf < 4; ++mf)
#pragma unroll
      for (int nf = 0; nf < 4; ++nf)
        acc[mf][nf] = __builtin_amdgcn_mfma_f32_16x16x32_f16(fa[mf], fb[nf], acc[mf][nf], 0, 0, 0);
    __builtin_amdgcn_s_barrier();
    cur ^= 1;
  }
  // vectorized epilogue: acc[mf][nf][0..3] are 4 consecutive l positions -> one dwordx4 store
  const int rb = m0 + wr * 64 + (lane >> 4) * 4;
  const int cb = n0 + wc * 64 + mlo;
#pragma unroll
  for (int mf = 0; mf < 4; ++mf)
#pragma unroll
    for (int nf = 0; nf < 4; ++nf) {
      int col = cb + nf * 16;
      int row = rb + mf * 16;
      int b = row >> 10, l = row & 1023;
      *(f32x4*)&out[((size_t)(b * DM + col)) * L_ + l] = acc[mf][nf];
    }
}

// ---------------- K2: depthwise conv; x-channels -> pre-swizzled XT fp16 tiles; B/C fp16 ----------------
#define CC 16
__global__ __launch_bounds__(256) void k_conv(
    const u16* __restrict__ xBC, const float* __restrict__ cw,
    const float* __restrict__ cb,
    u16* __restrict__ XTh,
    u16* __restrict__ Bh,
    u16* __restrict__ Chh)
{
  __shared__ float Ls[18][32][CC];
  const int t  = threadIdx.x;
  const int c0 = blockIdx.x * CC;
  const int h0 = blockIdx.y * 16;
  const int b  = blockIdx.z;
#pragma unroll
  for (int k = 0; k < 9; ++k) {
    int f = k * 256 + t;
    int fc4 = f & 3, fw = (f >> 2) & 31, fr = f >> 7;
    int h = h0 + fr - 1;
    U4 v; v.v = make_uint4(0, 0, 0, 0);
    if (h >= 0 && h < 32) {
      uint2 p = *(const uint2*)&xBC[((size_t)(b * 1024 + h * 32 + fw)) * CONVD + c0 + fc4 * 4];
      v.v.x = p.x; v.v.y = p.y;
    }
    Ls[fr][fw][fc4 * 4 + 0] = h2f(v.s[0]);
    Ls[fr][fw][fc4 * 4 + 1] = h2f(v.s[1]);
    Ls[fr][fw][fc4 * 4 + 2] = h2f(v.s[2]);
    Ls[fr][fw][fc4 * 4 + 3] = h2f(v.s[3]);
  }
  const int c4 = t & 3;
  const int w  = (t >> 2) & 31;
  const int hb = t >> 7;
  float wt[4][9];
  float bias[4];
#pragma unroll
  for (int j = 0; j < 4; ++j) {
    int c = c0 + c4 * 4 + j;
    bias[j] = cb[c];
#pragma unroll
    for (int kb = 0; kb < 9; ++kb) wt[j][kb] = cw[c * 9 + kb];
  }
  __syncthreads();
  const bool isx = (c0 < DI);
  u16 xh16[8][4];
#pragma unroll
  for (int k = 0; k < 8; ++k) {
    int h = hb * 8 + k;
    float acc[4] = {bias[0], bias[1], bias[2], bias[3]};
#pragma unroll
    for (int dh = 0; dh < 3; ++dh) {
#pragma unroll
      for (int dw = -1; dw <= 1; ++dw) {
        int ww = w + dw;
        if (ww < 0 || ww > 31) continue;
        const float* p = &Ls[h + dh][ww][c4 * 4];
        int kb = dh * 3 + (dw + 1);
#pragma unroll
        for (int j = 0; j < 4; ++j) acc[j] = fmaf(p[j], wt[j][kb], acc[j]);
      }
    }
    float s4[4];
#pragma unroll
    for (int j = 0; j < 4; ++j) { float v = acc[j]; s4[j] = v / (1.f + expf(-v)); }
    if (isx) {
#pragma unroll
      for (int j = 0; j < 4; ++j) xh16[k][j] = f2h(s4[j]);
    } else {
      size_t row = (size_t)b * 1024 + (h0 + h) * 32 + w;
      u16 hv[4] = {f2h(s4[0]), f2h(s4[1]), f2h(s4[2]), f2h(s4[3])};
      uint2 hp = make_uint2((u32)hv[0] | ((u32)hv[1] << 16), (u32)hv[2] | ((u32)hv[3] << 16));
      int c = c0 + c4 * 4;
      if (c < DI + DS) *(uint2*)&Bh[row * DS + (c - DI)] = hp;
      else             *(uint2*)&Chh[row * DS + (c - DI - DS)] = hp;
    }
  }
  if (isx) {
    __syncthreads();
    u16* Ls2 = (u16*)Ls;
#pragma unroll
    for (int k = 0; k < 8; ++k) {
      int pos = (hb * 8 + k) * 32 + w;
#pragma unroll
      for (int j = 0; j < 4; ++j)
        Ls2[(c4 * 4 + j) * 512 + pos] = xh16[k][j];
    }
    __syncthreads();
    const int hh = c0 >> 6;
    const int pb = c0 & 63;
#pragma unroll
    for (int i = 0; i < 4; ++i) {
      int cid = i * 256 + t;
      int pl = cid >> 6, rem = cid & 63;
      int jbl = rem >> 3, slot = rem & 7;
      int labs = h0 * 32 + jbl * 64;
      size_t tile = ((size_t)(b * 4 + (labs >> 8)) * NH + hh) * 4 + ((labs >> 6) & 3);
      *(uint4*)((char*)XTh + tile * 8192 + SWZ(pb + pl, slot)) =
          *(const uint4*)&Ls2[pl * 512 + jbl * 64 + slot * 8];
    }
  }
}

// stage one pre-swizzled 8KB XT tile into LDS via linear DMA
#define STAGE_XT(tileByte) do {                                                                   \
  _Pragma("unroll")                                                                               \
  for (int i_ = 0; i_ < 2; ++i_) {                                                                \
    int S_ = i_ * 256 + t;                                                                        \
    __builtin_amdgcn_global_load_lds(                                                             \
        (const __attribute__((address_space(1))) u32*)((const char*)XTh + (tileByte) + S_ * 16),  \
        (__attribute__((address_space(3))) u32*)((char*)Xh_t + S_ * 16), 16, 0, 0);               \
  }                                                                                               \
} while (0)

// ---------------- K5: chunk states via MFMA; fp16 output ----------------
__global__ __launch_bounds__(256) void k_states(
    const u16* __restrict__ XTh,
    const u16* __restrict__ Bh,
    const float* __restrict__ dt, const float* __restrict__ dAcs,
    u16* __restrict__ st16)
{
  __shared__ u16 bpackB[64 * 65];
  __shared__ u16 BTh_t[4096];
  __shared__ u16 Xh_t[4096];
  __shared__ float wall[256];
  const int bc = blockIdx.x;
  const int hh = blockIdx.y;
  const int t  = threadIdx.x;
  const int lane = t & 63, w = t >> 6;
  const int mlo = lane & 15, gg = lane >> 4;
  const int r = t >> 2, q = (t & 3) * 16;
  const size_t base = (size_t)bc * 256;
  const float last = dAcs[(base + 255) * NH + hh];
  wall[t] = __expf(last - dAcs[(base + t) * NH + hh]) * dt[(base + t) * NH + hh];
  f32x4 acc[4];
#pragma unroll
  for (int i = 0; i < 4; ++i) acc[i] = (f32x4){0.f, 0.f, 0.f, 0.f};
  for (int jt = 0; jt < 4; ++jt) {
    const int j0 = jt * 64;
    __syncthreads();
    STAGE_XT(((size_t)(bc * NH + hh) * 4 + jt) * 8192);
    {
      const u16* bhp = &Bh[(size_t)(base + j0 + r) * DS + q];
      U4 H0, H1;
      H0.v = *(const uint4*)bhp; H1.v = *(const uint4*)(bhp + 8);
#pragma unroll
      for (int k = 0; k < 8; ++k) {
        bpackB[r * 65 + q + k]     = H0.s[k];
        bpackB[r * 65 + q + 8 + k] = H1.s[k];
      }
    }
    __syncthreads();
#pragma unroll
    for (int c = 0; c < 2; ++c) {
      U4 BH;
#pragma unroll
      for (int jj = 0; jj < 8; ++jj) {
        int j = q + c * 8 + jj;
        BH.s[jj] = f2h(h2f(bpackB[j * 65 + r]) * wall[j0 + j]);
      }
      *(uint4*)((char*)BTh_t + SWZ(r, (q >> 3) + c)) = BH.v;
    }
    __syncthreads();
#pragma unroll
    for (int s = 0; s < 2; ++s) {
      f16x8 fah = *(const f16x8*)((const char*)Xh_t + SWZ(w * 16 + mlo, s * 4 + gg));
#pragma unroll
      for (int nf = 0; nf < 4; ++nf) {
        f16x8 fbh = *(const f16x8*)((const char*)BTh_t + SWZ(nf * 16 + mlo, s * 4 + gg));
        acc[nf] = __builtin_amdgcn_mfma_f32_16x16x32_f16(fah, fbh, acc[nf], 0, 0, 0);
      }
    }
  }
  const size_t sb = ((size_t)(bc * NH + hh)) << 12;
#pragma unroll
  for (int nf = 0; nf < 4; ++nf)
#pragma unroll
    for (int reg = 0; reg < 4; ++reg) {
      int p = w * 16 + (lane >> 4) * 4 + reg;
      int n = nf * 16 + mlo;
      st16[sb + (size_t)p * 64 + n] = f2h(acc[nf][reg]);
    }
}

// ---------------- K7: y = intra + inter + D*x; inline scan; BALANCED i-tile pair {z, 3-z} ----------------
__global__ __launch_bounds__(256) void k_y(
    const u16* __restrict__ XTh,
    const u16* __restrict__ Chg, const u16* __restrict__ Bhg,
    const float* __restrict__ dtp, const float* __restrict__ dAcs,
    const u16* __restrict__ st16, const float* __restrict__ cdec,
    const float* __restrict__ Dp,
    u16* __restrict__ y)
{
  __shared__ u16 Pb_t[4096];
  __shared__ u16 Xh_t[4096];
  __shared__ u16 att_t[4096];
  __shared__ float dAc_s[256], dt_s[256], ei_s[128];
  const int bc = blockIdx.x;
  const int hh = blockIdx.y;
  const int z  = blockIdx.z;
  const int itA = z;          // first i-tile  (z=0 -> 0, z=1 -> 1)
  const int itB = 3 - z;      // second i-tile (z=0 -> 3, z=1 -> 2); 5/5 pair-unit balance
  const int jtmax = itB;
  const int t  = threadIdx.x;
  const int lane = t & 63, w = t >> 6;
  const int mlo = lane & 15, gg = lane >> 4;
  const int r = t >> 2, q = (t & 3) * 16;
  const int slot0 = q >> 3;
  const size_t base = (size_t)bc * 256;
  {
    float da = dAcs[(base + t) * NH + hh];
    dAc_s[t] = da;
    dt_s[t]  = dtp[(base + t) * NH + hh];
    if (t < 128) {
      int ii = t >> 6, l = t & 63;
      int ita_ = ii ? itB : itA;
      ei_s[t] = __expf(dAcs[(base + ita_ * 64 + l) * NH + hh]);
    }
  }
  // inline inter-chunk scan: prev for this (bc,hh), 16 elems/thread
  {
    const int b = bc >> 2, cchunk = bc & 3;
    float carry[16];
#pragma unroll
    for (int k = 0; k < 16; ++k) carry[k] = 0.f;
    for (int c2 = 0; c2 < cchunk; ++c2) {            // uniform runtime loop
      float dec = cdec[(b * 4 + c2) * NH + hh];
      const u16* sp = &st16[(((size_t)((b * 4 + c2) * NH + hh)) << 12) + (size_t)r * 64 + q];
      U4 S0, S1;
      S0.v = *(const uint4*)sp; S1.v = *(const uint4*)(sp + 8);
#pragma unroll
      for (int k = 0; k < 8; ++k) {
        carry[k]     = carry[k]     * dec + h2f(S0.s[k]);
        carry[k + 8] = carry[k + 8] * dec + h2f(S1.s[k]);
      }
    }
    U4 H0, H1;
#pragma unroll
    for (int k = 0; k < 8; ++k) { H0.s[k] = f2h(carry[k]); H1.s[k] = f2h(carry[k + 8]); }
    *(uint4*)((char*)Pb_t + SWZ(r, slot0))     = H0.v;
    *(uint4*)((char*)Pb_t + SWZ(r, slot0 + 1)) = H1.v;
  }
  __syncthreads();
  f16x8 fc[2][2];
#pragma unroll
  for (int iti = 0; iti < 2; ++iti) {
    const int ita_ = iti ? itB : itA;
#pragma unroll
    for (int s = 0; s < 2; ++s)
      fc[iti][s] = *(const f16x8*)&Chg[(size_t)(base + ita_ * 64 + w * 16 + mlo) * DS +
                                       (s * 4 + gg) * 8];
  }
  f32x4 accy[2][4];
#pragma unroll
  for (int i = 0; i < 2; ++i)
#pragma unroll
    for (int j = 0; j < 4; ++j) accy[i][j] = (f32x4){0.f, 0.f, 0.f, 0.f};
#pragma unroll
  for (int s = 0; s < 2; ++s)
#pragma unroll
    for (int pf = 0; pf < 4; ++pf) {
      f16x8 fph = *(const f16x8*)((const char*)Pb_t + SWZ(pf * 16 + mlo, s * 4 + gg));
#pragma unroll
      for (int iti = 0; iti < 2; ++iti)
        accy[iti][pf] = __builtin_amdgcn_mfma_f32_16x16x32_f16(fc[iti][s], fph, accy[iti][pf], 0, 0, 0);
    }
  const int ilb = w * 16 + (lane >> 4) * 4;
#pragma unroll
  for (int iti = 0; iti < 2; ++iti)
#pragma unroll
    for (int pf = 0; pf < 4; ++pf)
#pragma unroll
      for (int reg = 0; reg < 4; ++reg)
        accy[iti][pf][reg] *= ei_s[iti * 64 + ilb + reg];

  u32 xdv[2][8];
  for (int jt = 0; jt <= jtmax; ++jt) {
    __syncthreads();
    STAGE_XT(((size_t)(bc * NH + hh) * 4 + jt) * 8192);
    {
      const u16* bh = &Bhg[(size_t)(base + jt * 64 + r) * DS + q];
      U4 V0, V1;
      V0.v = *(const uint4*)bh; V1.v = *(const uint4*)(bh + 8);
      float wj = dt_s[jt * 64 + r];
#pragma unroll
      for (int k = 0; k < 8; ++k) {
        V0.s[k] = f2h(h2f(V0.s[k]) * wj);
        V1.s[k] = f2h(h2f(V1.s[k]) * wj);
      }
      *(uint4*)((char*)Pb_t + SWZ(r, slot0))     = V0.v;
      *(uint4*)((char*)Pb_t + SWZ(r, slot0 + 1)) = V1.v;
    }
    __syncthreads();
#pragma unroll
    for (int iti = 0; iti < 2; ++iti) {
      const int ita_ = iti ? itB : itA;
      if (jt == ita_) {
#pragma unroll
        for (int pf = 0; pf < 4; ++pf)
#pragma unroll
          for (int rp = 0; rp < 2; ++rp) {
            int j0l = ilb + rp * 2;
            u16 a = *(const u16*)((const char*)Xh_t + SWZ(pf * 16 + mlo, j0l >> 3) + (j0l & 7) * 2);
            u16 b2 = *(const u16*)((const char*)Xh_t + SWZ(pf * 16 + mlo, (j0l + 1) >> 3) + ((j0l + 1) & 7) * 2);
            xdv[iti][pf * 2 + rp] = (u32)a | ((u32)b2 << 16);
          }
      }
    }
#pragma unroll
    for (int iti = 0; iti < 2; ++iti) {
      const int ita_ = iti ? itB : itA;
      if (jt > ita_) continue;
      f32x4 g[4];
#pragma unroll
      for (int i = 0; i < 4; ++i) g[i] = (f32x4){0.f, 0.f, 0.f, 0.f};
#pragma unroll
      for (int s = 0; s < 2; ++s)
#pragma unroll
        for (int jf = 0; jf < 4; ++jf) {
          f16x8 fbh = *(const f16x8*)((const char*)Pb_t + SWZ(jf * 16 + mlo, s * 4 + gg));
          g[jf] = __builtin_amdgcn_mfma_f32_16x16x32_f16(fc[iti][s], fbh, g[jf], 0, 0, 0);
        }
#pragma unroll
      for (int jf = 0; jf < 4; ++jf)
#pragma unroll
        for (int reg = 0; reg < 4; ++reg) {
          int il = ita_ * 64 + ilb + reg;
          int jl = jt * 64 + jf * 16 + mlo;
          float av = (jl <= il) ? g[jf][reg] * __expf(dAc_s[il] - dAc_s[jl]) : 0.f;
          *(u16*)((char*)att_t + SWZ(il & 63, (jl & 63) >> 3) + (jl & 7) * 2) = f2h(av);
        }
#pragma unroll
      for (int s = 0; s < 2; ++s) {
        f16x8 fa = *(const f16x8*)((const char*)att_t + SWZ(w * 16 + mlo, s * 4 + gg));
#pragma unroll
        for (int pf = 0; pf < 4; ++pf) {
          f16x8 fxh = *(const f16x8*)((const char*)Xh_t + SWZ(pf * 16 + mlo, s * 4 + gg));
          accy[iti][pf] = __builtin_amdgcn_mfma_f32_16x16x32_f16(fa, fxh, accy[iti][pf], 0, 0, 0);
        }
      }
    }
  }
  const float Dh = Dp[hh];
#pragma unroll
  for (int iti = 0; iti < 2; ++iti) {
    const int ita_ = iti ? itB : itA;
#pragma unroll
    for (int pf = 0; pf < 4; ++pf)
#pragma unroll
      for (int reg = 0; reg < 4; ++reg) {
        size_t row = base + ita_ * 64 + ilb + reg;
        int col = hh * HD + pf * 16 + mlo;
        u32 pk = xdv[iti][pf * 2 + (reg >> 1)];
        u16 xv = (reg & 1) ? (u16)(pk >> 16) : (u16)pk;
        y[row * DI + col] = f2h(accy[iti][pf][reg] + Dh * h2f(xv));
      }
  }
}

// ---------------- K8: LayerNorm * z (both fp16 in) -> single fp16 y ----------------
__global__ __launch_bounds__(256) void k_norm(
    const u16* __restrict__ z, const float* __restrict__ nw,
    const float* __restrict__ nb, const u16* __restrict__ y,
    u16* __restrict__ yh)
{
  __shared__ float rs[4], rq[4];
  const size_t row = blockIdx.x;
  const int t = threadIdx.x;
  float v[3];
  float s = 0.f, sq = 0.f;
#pragma unroll
  for (int r = 0; r < 3; ++r) {
    v[r] = h2f(y[row * DI + r * 256 + t]);
    s += v[r];
    sq = fmaf(v[r], v[r], sq);
  }
#pragma unroll
  for (int off = 32; off > 0; off >>= 1) {
    s  += __shfl_down(s, off, 64);
    sq += __shfl_down(sq, off, 64);
  }
  const int wid = t >> 6, lane = t & 63;
  if (lane == 0) { rs[wid] = s; rq[wid] = sq; }
  __syncthreads();
  if (t == 0) {
    rs[0] = rs[0] + rs[1] + rs[2] + rs[3];
    rq[0] = rq[0] + rq[1] + rq[2] + rq[3];
  }
  __syncthreads();
  const float mu   = rs[0] * (1.f / DI);
  const float var  = rq[0] * (1.f / DI) - mu * mu;
  const float rstd = 1.f / sqrtf(var + EPS_);
#pragma unroll
  for (int r = 0; r < 3; ++r) {
    int d = r * 256 + t;
    float o = (v[r] - mu) * rstd * nw[d] + nb[d];
    float p = o * h2f(z[row * DI + d]);
    yh[row * DI + d] = f2h(p);
  }
}

extern "C" void kernel_launch(void* const* d_in, const int* in_sizes, int n_in,
                              void* d_out, int out_size, void* d_ws, size_t ws_size,
                              hipStream_t stream)
{
  const float* u    = (const float*)d_in[0];
  const float* ipw  = (const float*)d_in[1];
  const float* cw   = (const float*)d_in[2];
  const float* cb   = (const float*)d_in[3];
  const float* dtb  = (const float*)d_in[4];
  const float* Alog = (const float*)d_in[5];
  const float* Dp   = (const float*)d_in[6];
  const float* nw   = (const float*)d_in[7];
  const float* nb   = (const float*)d_in[8];
  const float* opw  = (const float*)d_in[9];
  float* out = (float*)d_out;

  float* ws = (float*)d_ws;
  size_t off = 0;
  u16*   z16     = (u16*)(ws + off); off += (size_t)B_ * L_ * DI / 2;
  u16*   xBC16   = (u16*)(ws + off); off += (size_t)B_ * L_ * CONVD / 2;
  float* dt_buf  = ws + off; off += (size_t)B_ * L_ * NH;
  float* x_buf   = ws + off; off += (size_t)B_ * L_ * DI;     // alias space only
  u16*   y16     = (u16*)(ws + off); off += (size_t)B_ * L_ * DI / 2;
  u16*   Bh_buf  = (u16*)(ws + off); off += (size_t)B_ * L_ * DS / 2;
  u16*   Ch_buf  = (u16*)(ws + off); off += (size_t)B_ * L_ * DS / 2;
  float* dAcs    = ws + off; off += (size_t)B_ * L_ * NH;
  float* cdec    = ws + off; off += (size_t)B_ * NCH * NH;
  u16*   st16    = (u16*)(ws + off); off += (size_t)B_ * NCH * NH * HD * DS / 2;
  u16*   Woh     = (u16*)(ws + off); off += (size_t)DM * DI / 2;
  u16*   XTh_buf = (u16*)(ws + off); off += (size_t)B_ * NCH * NH * 4 * 4096 / 2;

  // aliases inside x_buf (dead/live windows don't overlap)
  u16* Ah = (u16*)x_buf;
  u16* Whip = Ah + (size_t)B_ * L_ * DM;
  u16* yh = (u16*)x_buf;                         // single fp16 y for out_proj

  hipLaunchKernelGGL(k_prep, dim3(3216), dim3(256), 0, stream,
                     u, ipw, opw, dtb, Alog, Ah, Whip, Woh, dt_buf, dAcs, cdec);
  hipLaunchKernelGGL(k_gemm1, dim3(128, 13), dim3(256), 0, stream,
                     Ah, Whip, z16, xBC16);
  hipLaunchKernelGGL(k_conv, dim3(56, 2, 16), dim3(256), 0, stream,
                     xBC16, cw, cb, XTh_buf, Bh_buf, Ch_buf);
  hipLaunchKernelGGL(k_states, dim3(64, 12), dim3(256), 0, stream,
                     XTh_buf, Bh_buf, dt_buf, dAcs, st16);
  hipLaunchKernelGGL(k_y, dim3(64, 12, 2), dim3(256), 0, stream,
                     XTh_buf, Ch_buf, Bh_buf, dt_buf, dAcs, st16, cdec, Dp, y16);
  hipLaunchKernelGGL(k_norm, dim3(16384), dim3(256), 0, stream, z16, nw, nb, y16, yh);
  hipLaunchKernelGGL(k_gemm2, dim3(128, 3), dim3(256), 0, stream, yh, Woh, out);
}